// Round 1
// baseline (1690.835 us; speedup 1.0000x reference)
//
#include <hip/hip_runtime.h>
#include <math.h>

#define CIN   256
#define COUT  256
#define H     64
#define W     64
#define HW    4096
#define KK    9
#define KC    2304      // CIN * KK
#define NOFF  27        // 3*K*K offset/mask channels
#define B_    4
#define GROUPS 16
#define EPS   1e-5f

// ---------------------------------------------------------------------------
// Kernel A: offset/mask conv  om[b][oc][i][j], oc in [0,27)
// grid: 4*27*4096/256 = 1728 blocks of 256
// ---------------------------------------------------------------------------
__global__ __launch_bounds__(256) void offconv_kernel(
    const float* __restrict__ x, const float* __restrict__ w_off,
    const float* __restrict__ b_off, float* __restrict__ om) {
  int n  = blockIdx.x * 256 + threadIdx.x;       // ((b*27+oc)*64+i)*64+j
  int j  = n & 63;
  int i  = (n >> 6) & 63;
  int oc = (n >> 12) % NOFF;
  int b  = n / (NOFF * HW);
  const float* xb = x + b * CIN * HW;
  const float* wbase = w_off + oc * CIN * KK;    // wave-uniform
  float acc = b_off[oc];
  for (int c = 0; c < CIN; ++c) {
    const float* xc = xb + c * HW;
    const float* wc = wbase + c * KK;
#pragma unroll
    for (int ky = 0; ky < 3; ++ky) {
      int yy = i + ky - 1;
      if ((unsigned)yy >= (unsigned)H) continue;
#pragma unroll
      for (int kx = 0; kx < 3; ++kx) {
        int xx = j + kx - 1;
        if ((unsigned)xx >= (unsigned)W) continue;
        acc += xc[yy * W + xx] * wc[ky * 3 + kx];
      }
    }
  }
  om[n] = acc;
}

// ---------------------------------------------------------------------------
// Kernel B: deformable sampling + conv accumulation.
// Each block: 4 contiguous output pixels (b, i, j0..j0+3), 256 threads.
// Phase 0: 36 threads compute tap coords/weights (mask folded in).
// Phase 1: all threads gather bilinear samples into LDS s[4][2304].
// Phase 2: thread t = output channel co; 2304-deep dot per pixel.
// grid: 16384/4 = 4096 blocks
// ---------------------------------------------------------------------------
__global__ __launch_bounds__(256) void dcn_kernel(
    const float* __restrict__ x, const float* __restrict__ om,
    const float* __restrict__ weight, const float* __restrict__ bias,
    float* __restrict__ convout) {
  __shared__ float s[4][KC];
  __shared__ float tw[4][KK][4];
  __shared__ int   tc[4][KK][2];

  int flat = blockIdx.x;
  int j0 = (flat & 15) * 4;
  int i  = (flat >> 4) & 63;
  int b  = flat >> 10;
  int t  = threadIdx.x;

  const float* xb  = x + b * CIN * HW;
  const float* omb = om + b * NOFF * HW;

  if (t < 36) {
    int p = t / 9, k = t % 9;
    int pix = i * W + j0 + p;
    float offy = omb[k * HW + pix];
    float offx = omb[(9 + k) * HW + pix];
    float mval = omb[(18 + k) * HW + pix];
    float mask = 1.f / (1.f + expf(-mval));
    float py = (float)(i - 1 + k / 3) + offy;
    float px = (float)(j0 + p - 1 + k % 3) + offx;
    float y0f = floorf(py), x0f = floorf(px);
    float wy1 = py - y0f, wx1 = px - x0f;
    tw[p][k][0] = (1.f - wy1) * (1.f - wx1) * mask;
    tw[p][k][1] = (1.f - wy1) * wx1 * mask;
    tw[p][k][2] = wy1 * (1.f - wx1) * mask;
    tw[p][k][3] = wy1 * wx1 * mask;
    tc[p][k][0] = (int)y0f;
    tc[p][k][1] = (int)x0f;
  }
  __syncthreads();

  // Phase 1: fill s[p][kc], kc = c*9 + k  (matches weight[co][c][k] layout)
#pragma unroll
  for (int p = 0; p < 4; ++p) {
    for (int r = 0; r < 9; ++r) {
      int kc = t + 256 * r;
      int c = kc / 9, k = kc % 9;
      int y0 = tc[p][k][0], x0 = tc[p][k][1];
      float w00 = tw[p][k][0], w01 = tw[p][k][1];
      float w10 = tw[p][k][2], w11 = tw[p][k][3];
      const float* xc = xb + c * HW;
      float v = 0.f;
      bool y0ok = (unsigned)y0 < (unsigned)H;
      bool y1ok = (unsigned)(y0 + 1) < (unsigned)H;
      bool x0ok = (unsigned)x0 < (unsigned)W;
      bool x1ok = (unsigned)(x0 + 1) < (unsigned)W;
      if (y0ok) {
        const float* row = xc + y0 * W;
        if (x0ok) v += w00 * row[x0];
        if (x1ok) v += w01 * row[x0 + 1];
      }
      if (y1ok) {
        const float* row = xc + (y0 + 1) * W;
        if (x0ok) v += w10 * row[x0];
        if (x1ok) v += w11 * row[x0 + 1];
      }
      s[p][kc] = v;
    }
  }
  __syncthreads();

  // Phase 2: each thread = one output channel, 4 pixel accumulators
  int co = t;
  float bco = bias[co];
  float acc0 = bco, acc1 = bco, acc2 = bco, acc3 = bco;
  const float4* wrow = (const float4*)(weight + co * KC);
  const float4* sp0 = (const float4*)s[0];
  const float4* sp1 = (const float4*)s[1];
  const float4* sp2 = (const float4*)s[2];
  const float4* sp3 = (const float4*)s[3];
#pragma unroll 4
  for (int q = 0; q < KC / 4; ++q) {
    float4 wv = wrow[q];
    float4 a0 = sp0[q], a1 = sp1[q], a2 = sp2[q], a3 = sp3[q];
    acc0 += wv.x * a0.x + wv.y * a0.y + wv.z * a0.z + wv.w * a0.w;
    acc1 += wv.x * a1.x + wv.y * a1.y + wv.z * a1.z + wv.w * a1.w;
    acc2 += wv.x * a2.x + wv.y * a2.y + wv.z * a2.z + wv.w * a2.w;
    acc3 += wv.x * a3.x + wv.y * a3.y + wv.z * a3.z + wv.w * a3.w;
  }
  float4 o = make_float4(acc0, acc1, acc2, acc3);
  *(float4*)&convout[((b * COUT + co) * H + i) * W + j0] = o;
}

// ---------------------------------------------------------------------------
// Kernel C: GroupNorm(16). One block per (b, g): 16 ch * 4096 = 65536 elems.
// grid: 64 blocks of 256
// ---------------------------------------------------------------------------
__global__ __launch_bounds__(256) void gn_kernel(
    const float* __restrict__ convout, const float* __restrict__ gamma,
    const float* __restrict__ beta, float* __restrict__ out) {
  int bg = blockIdx.x;
  int b = bg >> 4, g = bg & 15;
  const float* base = convout + (size_t)(b * COUT + g * 16) * HW;
  float* obase = out + (size_t)(b * COUT + g * 16) * HW;
  int t = threadIdx.x;

  float sum = 0.f, sq = 0.f;
  for (int r = 0; r < 256; ++r) {
    float v = base[t + 256 * r];
    sum += v;
    sq += v * v;
  }
#pragma unroll
  for (int off = 32; off > 0; off >>= 1) {
    sum += __shfl_down(sum, off, 64);
    sq  += __shfl_down(sq, off, 64);
  }
  __shared__ float red_s[2][4];
  __shared__ float mu_s, rs_s;
  int wid = t >> 6, lane = t & 63;
  if (lane == 0) { red_s[0][wid] = sum; red_s[1][wid] = sq; }
  __syncthreads();
  if (t == 0) {
    float S = red_s[0][0] + red_s[0][1] + red_s[0][2] + red_s[0][3];
    float Q = red_s[1][0] + red_s[1][1] + red_s[1][2] + red_s[1][3];
    float mu = S * (1.f / 65536.f);
    float var = Q * (1.f / 65536.f) - mu * mu;
    mu_s = mu;
    rs_s = rsqrtf(var + EPS);
  }
  __syncthreads();
  float mu = mu_s, rs = rs_s;
  for (int r = 0; r < 256; ++r) {
    int e = t + 256 * r;
    int cg = e >> 12;                 // e / 4096
    int c = g * 16 + cg;
    float v = base[e];
    obase[e] = (v - mu) * rs * gamma[c] + beta[c];
  }
}

// ---------------------------------------------------------------------------
extern "C" void kernel_launch(void* const* d_in, const int* in_sizes, int n_in,
                              void* d_out, int out_size, void* d_ws, size_t ws_size,
                              hipStream_t stream) {
  const float* x      = (const float*)d_in[0];
  const float* w_off  = (const float*)d_in[1];
  const float* b_off  = (const float*)d_in[2];
  const float* weight = (const float*)d_in[3];
  const float* bias   = (const float*)d_in[4];
  const float* gamma  = (const float*)d_in[5];
  const float* beta   = (const float*)d_in[6];
  float* out = (float*)d_out;

  float* om      = (float*)d_ws;                       // 4*27*4096 floats = 1.77 MB
  float* convout = om + (size_t)B_ * NOFF * HW;        // 4*256*4096 floats = 16.8 MB

  offconv_kernel<<<dim3(B_ * NOFF * HW / 256), dim3(256), 0, stream>>>(x, w_off, b_off, om);
  dcn_kernel<<<dim3(B_ * HW / 4), dim3(256), 0, stream>>>(x, om, weight, bias, convout);
  gn_kernel<<<dim3(B_ * GROUPS), dim3(256), 0, stream>>>(convout, gamma, beta, out);
}

// Round 2
// 660.175 us; speedup vs baseline: 2.5612x; 2.5612x over previous
//
#include <hip/hip_runtime.h>
#include <math.h>

#define CIN   256
#define COUT  256
#define H     64
#define W     64
#define HW    4096
#define KK    9
#define KC    2304      // CIN * KK
#define NOFF  27
#define B_    4
#define GROUPS 16
#define EPS   1e-5f
#define MT    32        // pixels per block (half an image row)

typedef __attribute__((ext_vector_type(4))) float f32x4;
typedef __attribute__((ext_vector_type(8))) short s16x8;

static __device__ __forceinline__ unsigned short f2bf(float f) {
  unsigned u = __builtin_bit_cast(unsigned, f);
  u += 0x7FFF + ((u >> 16) & 1);          // round-to-nearest-even
  return (unsigned short)(u >> 16);
}

// ---------------------------------------------------------------------------
// Kernel A: offset/mask conv (unchanged this round)
// ---------------------------------------------------------------------------
__global__ __launch_bounds__(256) void offconv_kernel(
    const float* __restrict__ x, const float* __restrict__ w_off,
    const float* __restrict__ b_off, float* __restrict__ om) {
  int n  = blockIdx.x * 256 + threadIdx.x;       // ((b*27+oc)*64+i)*64+j
  int j  = n & 63;
  int i  = (n >> 6) & 63;
  int oc = (n >> 12) % NOFF;
  int b  = n / (NOFF * HW);
  const float* xb = x + b * CIN * HW;
  const float* wbase = w_off + oc * CIN * KK;
  float acc = b_off[oc];
  for (int c = 0; c < CIN; ++c) {
    const float* xc = xb + c * HW;
    const float* wc = wbase + c * KK;
#pragma unroll
    for (int ky = 0; ky < 3; ++ky) {
      int yy = i + ky - 1;
      if ((unsigned)yy >= (unsigned)H) continue;
#pragma unroll
      for (int kx = 0; kx < 3; ++kx) {
        int xx = j + kx - 1;
        if ((unsigned)xx >= (unsigned)W) continue;
        acc += xc[yy * W + xx] * wc[ky * 3 + kx];
      }
    }
  }
  om[n] = acc;
}

// ---------------------------------------------------------------------------
// Kernel W: weight -> bf16, reordered tap-major: wTT[co][k*256+c]
// ---------------------------------------------------------------------------
__global__ __launch_bounds__(256) void wconv_kernel(
    const float* __restrict__ w, unsigned short* __restrict__ wTT) {
  int idx = blockIdx.x * 256 + threadIdx.x;      // co*2304 + k*256 + c
  int c  = idx & 255;
  int k  = (idx >> 8) % 9;
  int co = idx / KC;
  wTT[idx] = f2bf(w[(co * 256 + c) * 9 + k]);
}

// ---------------------------------------------------------------------------
// Kernel B: deformable conv via bf16 MFMA.
// Block: MT=32 pixels x 256 Cout, 256 threads (4 waves, each 32x64).
// K-order: k' = tap*256 + c. Per tap: one bilinear coord/mask per pixel
// (LDS tables), 8 chunks of 32 channels.
// grid: 4*64*2 = 512 blocks
// ---------------------------------------------------------------------------
__global__ __launch_bounds__(256, 2) void dcn_mfma_kernel(
    const float* __restrict__ x, const float* __restrict__ om,
    const unsigned short* __restrict__ wTT, const float* __restrict__ bias,
    float* __restrict__ convout) {
  __shared__ unsigned short Atile[MT][40];       // [pixel][k] bf16, pad 32->40
  __shared__ unsigned short Btile[256][40];      // [co][k]    bf16, pad 32->40
  __shared__ float tww[MT][KK][4];               // corner weights * mask
  __shared__ int   tcc[MT][KK][2];               // base addr, packed deltas

  int bi = blockIdx.x;
  int b  = bi >> 7;
  int i  = (bi >> 1) & 63;
  int j0 = (bi & 1) * MT;
  int t  = threadIdx.x;
  int lane = t & 63;
  int wv = t >> 6;

  const float* xb  = x + b * CIN * HW;
  const float* omb = om + b * NOFF * HW;

  // --- tap tables: MT*9 = 288 items ---
  for (int idx = t; idx < MT * KK; idx += 256) {
    int p = idx / KK, k = idx % KK;
    int pix = i * W + j0 + p;
    float offy = omb[k * HW + pix];
    float offx = omb[(9 + k) * HW + pix];
    float mval = omb[(18 + k) * HW + pix];
    float mask = 1.f / (1.f + __expf(-mval));
    float py = (float)(i - 1 + k / 3) + offy;
    float px = (float)(j0 + p - 1 + k % 3) + offx;
    float y0f = floorf(py), x0f = floorf(px);
    float wy1 = py - y0f, wx1 = px - x0f;
    int y0 = (int)y0f, x0 = (int)x0f;
    bool y0ok = (unsigned)y0 < (unsigned)H;
    bool y1ok = (unsigned)(y0 + 1) < (unsigned)H;
    bool x0ok = (unsigned)x0 < (unsigned)W;
    bool x1ok = (unsigned)(x0 + 1) < (unsigned)W;
    tww[p][k][0] = (1.f - wy1) * (1.f - wx1) * mask * (float)(y0ok && x0ok);
    tww[p][k][1] = (1.f - wy1) * wx1 * mask * (float)(y0ok && x1ok);
    tww[p][k][2] = wy1 * (1.f - wx1) * mask * (float)(y1ok && x0ok);
    tww[p][k][3] = wy1 * wx1 * mask * (float)(y1ok && x1ok);
    int y0c = min(max(y0, 0), H - 1);
    int y1c = min(max(y0 + 1, 0), H - 1);
    int x0c = min(max(x0, 0), W - 1);
    int x1c = min(max(x0 + 1, 0), W - 1);
    tcc[p][k][0] = y0c * W + x0c;
    tcc[p][k][1] = (x1c - x0c) | (((y1c - y0c) * W) << 8);
  }
  __syncthreads();

  f32x4 acc[2][4] = {};

  // sampling role: p = t>>3 (32 pixels), cseg = t&7 (4 channels each)
  int sp = t >> 3, scs = t & 7;
  // B staging role: cob = t>>2 (64 co per round), seg = t&3 (8 bf16 each)
  int cob = t >> 2, seg = t & 3;

  for (int kt = 0; kt < KK; ++kt) {
    float w00 = tww[sp][kt][0], w01 = tww[sp][kt][1];
    float w10 = tww[sp][kt][2], w11 = tww[sp][kt][3];
    int a00 = tcc[sp][kt][0];
    int dpk = tcc[sp][kt][1];
    int dx = dpk & 0xff, dy = dpk >> 8;
    const float* xtap = xb + a00;

    for (int cc = 0; cc < 8; ++cc) {
      int k0 = kt * 256 + cc * 32;
      // --- stage B: Btile[co][0..31] = wTT[co][k0..k0+31] ---
      {
        const unsigned short* src = wTT + cob * KC + k0 + seg * 8;
#pragma unroll
        for (int it = 0; it < 4; ++it) {
          *(uint4*)&Btile[cob + 64 * it][seg * 8] =
              *(const uint4*)(src + it * 64 * KC);
        }
      }
      // --- stage A: bilinear sample 4 channels for pixel sp ---
      {
        const float* base = xtap + (cc * 32 + scs * 4) * HW;
        ushort4 sv;
        {
          const float* bq = base;
          sv.x = f2bf(w00 * bq[0] + w01 * bq[dx] + w10 * bq[dy] + w11 * bq[dy + dx]);
        }
        {
          const float* bq = base + HW;
          sv.y = f2bf(w00 * bq[0] + w01 * bq[dx] + w10 * bq[dy] + w11 * bq[dy + dx]);
        }
        {
          const float* bq = base + 2 * HW;
          sv.z = f2bf(w00 * bq[0] + w01 * bq[dx] + w10 * bq[dy] + w11 * bq[dy + dx]);
        }
        {
          const float* bq = base + 3 * HW;
          sv.w = f2bf(w00 * bq[0] + w01 * bq[dx] + w10 * bq[dy] + w11 * bq[dy + dx]);
        }
        *(ushort4*)&Atile[sp][scs * 4] = sv;
      }
      __syncthreads();
      // --- MFMA: wave wv covers co in [wv*64, wv*64+64) ---
      {
        int lr = lane & 15, lq = lane >> 4;
        s16x8 afrag[2], bfrag[4];
#pragma unroll
        for (int tm = 0; tm < 2; ++tm)
          afrag[tm] = *(const s16x8*)&Atile[tm * 16 + lr][lq * 8];
#pragma unroll
        for (int tn = 0; tn < 4; ++tn)
          bfrag[tn] = *(const s16x8*)&Btile[wv * 64 + tn * 16 + lr][lq * 8];
#pragma unroll
        for (int tm = 0; tm < 2; ++tm)
#pragma unroll
          for (int tn = 0; tn < 4; ++tn)
            acc[tm][tn] = __builtin_amdgcn_mfma_f32_16x16x32_bf16(
                afrag[tm], bfrag[tn], acc[tm][tn], 0, 0, 0);
      }
      __syncthreads();
    }
  }

  // --- epilogue: D row=(lane>>4)*4+reg (pixel), col=lane&15 (co) ---
  {
    int lr = lane & 15, lq = lane >> 4;
#pragma unroll
    for (int tn = 0; tn < 4; ++tn) {
      int co = wv * 64 + tn * 16 + lr;
      float bco = bias[co];
      float* obase = convout + (size_t)(b * COUT + co) * HW + i * W + j0;
#pragma unroll
      for (int tm = 0; tm < 2; ++tm)
#pragma unroll
        for (int r = 0; r < 4; ++r) {
          int m = tm * 16 + lq * 4 + r;
          obase[m] = acc[tm][tn][r] + bco;
        }
    }
  }
}

// ---------------------------------------------------------------------------
// Kernel C: GroupNorm(16) (unchanged)
// ---------------------------------------------------------------------------
__global__ __launch_bounds__(256) void gn_kernel(
    const float* __restrict__ convout, const float* __restrict__ gamma,
    const float* __restrict__ beta, float* __restrict__ out) {
  int bg = blockIdx.x;
  int b = bg >> 4, g = bg & 15;
  const float* base = convout + (size_t)(b * COUT + g * 16) * HW;
  float* obase = out + (size_t)(b * COUT + g * 16) * HW;
  int t = threadIdx.x;

  float sum = 0.f, sq = 0.f;
  for (int r = 0; r < 256; ++r) {
    float v = base[t + 256 * r];
    sum += v;
    sq += v * v;
  }
#pragma unroll
  for (int off = 32; off > 0; off >>= 1) {
    sum += __shfl_down(sum, off, 64);
    sq  += __shfl_down(sq, off, 64);
  }
  __shared__ float red_s[2][4];
  __shared__ float mu_s, rs_s;
  int wid = t >> 6, lane = t & 63;
  if (lane == 0) { red_s[0][wid] = sum; red_s[1][wid] = sq; }
  __syncthreads();
  if (t == 0) {
    float S = red_s[0][0] + red_s[0][1] + red_s[0][2] + red_s[0][3];
    float Q = red_s[1][0] + red_s[1][1] + red_s[1][2] + red_s[1][3];
    float mu = S * (1.f / 65536.f);
    float var = Q * (1.f / 65536.f) - mu * mu;
    mu_s = mu;
    rs_s = rsqrtf(var + EPS);
  }
  __syncthreads();
  float mu = mu_s, rs = rs_s;
  for (int r = 0; r < 256; ++r) {
    int e = t + 256 * r;
    int cg = e >> 12;
    int c = g * 16 + cg;
    float v = base[e];
    obase[e] = (v - mu) * rs * gamma[c] + beta[c];
  }
}

// ---------------------------------------------------------------------------
extern "C" void kernel_launch(void* const* d_in, const int* in_sizes, int n_in,
                              void* d_out, int out_size, void* d_ws, size_t ws_size,
                              hipStream_t stream) {
  const float* x      = (const float*)d_in[0];
  const float* w_off  = (const float*)d_in[1];
  const float* b_off  = (const float*)d_in[2];
  const float* weight = (const float*)d_in[3];
  const float* bias   = (const float*)d_in[4];
  const float* gamma  = (const float*)d_in[5];
  const float* beta   = (const float*)d_in[6];
  float* out = (float*)d_out;

  float* om      = (float*)d_ws;                        // 4*27*4096 f32 = 1.77 MB
  float* convout = om + (size_t)B_ * NOFF * HW;         // 4*256*4096 f32 = 16.8 MB
  unsigned short* wTT = (unsigned short*)(convout + (size_t)B_ * COUT * HW); // 1.18 MB

  wconv_kernel<<<dim3(COUT * KC / 256), dim3(256), 0, stream>>>(weight, wTT);
  offconv_kernel<<<dim3(B_ * NOFF * HW / 256), dim3(256), 0, stream>>>(x, w_off, b_off, om);
  dcn_mfma_kernel<<<dim3(B_ * 64 * 2), dim3(256), 0, stream>>>(x, om, wTT, bias, convout);
  gn_kernel<<<dim3(B_ * GROUPS), dim3(256), 0, stream>>>(convout, gamma, beta, out);
}

// Round 3
// 411.049 us; speedup vs baseline: 4.1135x; 1.6061x over previous
//
#include <hip/hip_runtime.h>
#include <math.h>

#define CIN   256
#define COUT  256
#define H     64
#define W     64
#define HW    4096
#define KK    9
#define KC    2304      // CIN * KK
#define NOFF  27
#define B_    4
#define GROUPS 16
#define EPS   1e-5f
#define MT    32        // pixels per block (half an image row)

typedef __attribute__((ext_vector_type(4))) float f32x4;
typedef __attribute__((ext_vector_type(8))) short s16x8;

static __device__ __forceinline__ unsigned short f2bf(float f) {
  unsigned u = __builtin_bit_cast(unsigned, f);
  u += 0x7FFF + ((u >> 16) & 1);          // round-to-nearest-even
  return (unsigned short)(u >> 16);
}
static __device__ __forceinline__ float bf2f(unsigned short h) {
  return __builtin_bit_cast(float, (unsigned)h << 16);
}

// ---------------------------------------------------------------------------
// Kernel W: weight prep + gstat zero.
//  blocks [0,2304):      wTT[co][k*256+c] = bf16(weight[co][c][k])
//  blocks [2304,2592):   wOT[oc][k*256+c] = bf16(w_off[oc][c][k]), oc<32 pad0
//  block 2592:           gstat[0..127] = 0
// ---------------------------------------------------------------------------
__global__ __launch_bounds__(256) void wprep_kernel(
    const float* __restrict__ w, const float* __restrict__ w_off,
    unsigned short* __restrict__ wTT, unsigned short* __restrict__ wOT,
    float* __restrict__ gstat) {
  int bi = blockIdx.x;
  if (bi < 2304) {
    int idx = bi * 256 + threadIdx.x;          // co*2304 + k*256 + c
    int c  = idx & 255;
    int k  = (idx >> 8) % 9;
    int co = idx / KC;
    wTT[idx] = f2bf(w[(co * 256 + c) * 9 + k]);
  } else if (bi < 2304 + 288) {
    int idx = (bi - 2304) * 256 + threadIdx.x; // oc*2304 + k*256 + c
    int oc = idx / KC;
    int rem = idx % KC;
    int k = rem >> 8;
    int c = rem & 255;
    wOT[idx] = (oc < NOFF) ? f2bf(w_off[(oc * 256 + c) * 9 + k]) : (unsigned short)0;
  } else {
    if (threadIdx.x < 128) gstat[threadIdx.x] = 0.f;
  }
}

// ---------------------------------------------------------------------------
// Kernel A: offset/mask conv as bf16 MFMA GEMM.
// M=16384 pixels, N=32 (27 padded), K=2304 (k' = tap*256 + c).
// Block: 32 pixels x 32 oc, 256 threads = 4 waves; wave wv -> tile
// (tm=wv&1, tn=wv>>1) of 16x16. A split hi+lo bf16 for coordinate accuracy.
// grid: 512
// ---------------------------------------------------------------------------
__global__ __launch_bounds__(256, 2) void offconv_mfma_kernel(
    const float* __restrict__ x, const unsigned short* __restrict__ wOT,
    const float* __restrict__ b_off, float* __restrict__ om) {
  __shared__ unsigned short Ahi[MT][40];
  __shared__ unsigned short Alo[MT][40];
  __shared__ unsigned short Btile[32][40];

  int bi = blockIdx.x;
  int b  = bi >> 7;
  int i  = (bi >> 1) & 63;
  int j0 = (bi & 1) * MT;
  int t  = threadIdx.x;
  int lane = t & 63, wv = t >> 6;
  int tm = wv & 1, tn = wv >> 1;
  const float* xb = x + b * CIN * HW;

  f32x4 acc = {};
  int sp = t >> 3, scs = t & 7;     // staging: pixel sp, channels scs*4..+3

  for (int kt = 0; kt < KK; ++kt) {
    int ky = kt / 3, kx = kt % 3;
    int yy = i - 1 + ky;
    int xx = j0 + sp - 1 + kx;
    bool ok = ((unsigned)yy < (unsigned)H) && ((unsigned)xx < (unsigned)W);
    const float* src = xb + (ok ? yy * W + xx : 0);

    for (int cc = 0; cc < 8; ++cc) {
      // stage B: row=t>>3, 4 bf16 at (t&7)*4
      *(ushort4*)&Btile[t >> 3][(t & 7) * 4] =
          *(const ushort4*)(wOT + (t >> 3) * KC + kt * 256 + cc * 32 + (t & 7) * 4);
      // stage A hi/lo
      {
        int c0 = cc * 32 + scs * 4;
        ushort4 hv, lv;
#pragma unroll
        for (int q = 0; q < 4; ++q) {
          float v = ok ? src[(c0 + q) * HW] : 0.f;
          unsigned short h = f2bf(v);
          unsigned short l = f2bf(v - bf2f(h));
          ((unsigned short*)&hv)[q] = h;
          ((unsigned short*)&lv)[q] = l;
        }
        *(ushort4*)&Ahi[sp][scs * 4] = hv;
        *(ushort4*)&Alo[sp][scs * 4] = lv;
      }
      __syncthreads();
      {
        int lr = lane & 15, lq = lane >> 4;
        s16x8 bfr = *(const s16x8*)&Btile[tn * 16 + lr][lq * 8];
        s16x8 ah  = *(const s16x8*)&Ahi[tm * 16 + lr][lq * 8];
        s16x8 al  = *(const s16x8*)&Alo[tm * 16 + lr][lq * 8];
        acc = __builtin_amdgcn_mfma_f32_16x16x32_bf16(ah, bfr, acc, 0, 0, 0);
        acc = __builtin_amdgcn_mfma_f32_16x16x32_bf16(al, bfr, acc, 0, 0, 0);
      }
      __syncthreads();
    }
  }
  // epilogue: row=(lane>>4)*4+r -> pixel (within 16-tile), col=lane&15 -> oc
  {
    int lr = lane & 15, lq = lane >> 4;
    int oc = tn * 16 + lr;
    if (oc < NOFF) {
      float bo = b_off[oc];
      float* obase = om + (size_t)(b * NOFF + oc) * HW + i * W + j0 + tm * 16;
#pragma unroll
      for (int r = 0; r < 4; ++r)
        obase[lq * 4 + r] = acc[r] + bo;
    }
  }
}

// ---------------------------------------------------------------------------
// Kernel B: deformable conv via bf16 MFMA + fused GroupNorm partial stats.
// Block: MT=32 pixels x 256 Cout, 256 threads (4 waves, each 32x64).
// grid: 512
// ---------------------------------------------------------------------------
__global__ __launch_bounds__(256, 2) void dcn_mfma_kernel(
    const float* __restrict__ x, const float* __restrict__ om,
    const unsigned short* __restrict__ wTT, const float* __restrict__ bias,
    float* __restrict__ convout, float* __restrict__ gstat) {
  __shared__ unsigned short Atile[MT][40];
  __shared__ unsigned short Btile[256][40];
  __shared__ float tww[MT][KK][4];
  __shared__ int   tcc[MT][KK][2];

  int bi = blockIdx.x;
  int b  = bi >> 7;
  int i  = (bi >> 1) & 63;
  int j0 = (bi & 1) * MT;
  int t  = threadIdx.x;
  int lane = t & 63;
  int wv = t >> 6;

  const float* xb  = x + b * CIN * HW;
  const float* omb = om + b * NOFF * HW;

  for (int idx = t; idx < MT * KK; idx += 256) {
    int p = idx / KK, k = idx % KK;
    int pix = i * W + j0 + p;
    float offy = omb[k * HW + pix];
    float offx = omb[(9 + k) * HW + pix];
    float mval = omb[(18 + k) * HW + pix];
    float mask = 1.f / (1.f + __expf(-mval));
    float py = (float)(i - 1 + k / 3) + offy;
    float px = (float)(j0 + p - 1 + k % 3) + offx;
    float y0f = floorf(py), x0f = floorf(px);
    float wy1 = py - y0f, wx1 = px - x0f;
    int y0 = (int)y0f, x0 = (int)x0f;
    bool y0ok = (unsigned)y0 < (unsigned)H;
    bool y1ok = (unsigned)(y0 + 1) < (unsigned)H;
    bool x0ok = (unsigned)x0 < (unsigned)W;
    bool x1ok = (unsigned)(x0 + 1) < (unsigned)W;
    tww[p][k][0] = (1.f - wy1) * (1.f - wx1) * mask * (float)(y0ok && x0ok);
    tww[p][k][1] = (1.f - wy1) * wx1 * mask * (float)(y0ok && x1ok);
    tww[p][k][2] = wy1 * (1.f - wx1) * mask * (float)(y1ok && x0ok);
    tww[p][k][3] = wy1 * wx1 * mask * (float)(y1ok && x1ok);
    int y0c = min(max(y0, 0), H - 1);
    int y1c = min(max(y0 + 1, 0), H - 1);
    int x0c = min(max(x0, 0), W - 1);
    int x1c = min(max(x0 + 1, 0), W - 1);
    tcc[p][k][0] = y0c * W + x0c;
    tcc[p][k][1] = (x1c - x0c) | (((y1c - y0c) * W) << 8);
  }
  __syncthreads();

  f32x4 acc[2][4] = {};

  int sp = t >> 3, scs = t & 7;
  int cob = t >> 2, seg = t & 3;

  for (int kt = 0; kt < KK; ++kt) {
    float w00 = tww[sp][kt][0], w01 = tww[sp][kt][1];
    float w10 = tww[sp][kt][2], w11 = tww[sp][kt][3];
    int a00 = tcc[sp][kt][0];
    int dpk = tcc[sp][kt][1];
    int dx = dpk & 0xff, dy = dpk >> 8;
    const float* xtap = xb + a00;

    for (int cc = 0; cc < 8; ++cc) {
      int k0 = kt * 256 + cc * 32;
      {
        const unsigned short* src = wTT + cob * KC + k0 + seg * 8;
#pragma unroll
        for (int it = 0; it < 4; ++it) {
          *(uint4*)&Btile[cob + 64 * it][seg * 8] =
              *(const uint4*)(src + it * 64 * KC);
        }
      }
      {
        const float* base = xtap + (cc * 32 + scs * 4) * HW;
        ushort4 sv;
        {
          const float* bq = base;
          sv.x = f2bf(w00 * bq[0] + w01 * bq[dx] + w10 * bq[dy] + w11 * bq[dy + dx]);
        }
        {
          const float* bq = base + HW;
          sv.y = f2bf(w00 * bq[0] + w01 * bq[dx] + w10 * bq[dy] + w11 * bq[dy + dx]);
        }
        {
          const float* bq = base + 2 * HW;
          sv.z = f2bf(w00 * bq[0] + w01 * bq[dx] + w10 * bq[dy] + w11 * bq[dy + dx]);
        }
        {
          const float* bq = base + 3 * HW;
          sv.w = f2bf(w00 * bq[0] + w01 * bq[dx] + w10 * bq[dy] + w11 * bq[dy + dx]);
        }
        *(ushort4*)&Atile[sp][scs * 4] = sv;
      }
      __syncthreads();
      {
        int lr = lane & 15, lq = lane >> 4;
        s16x8 afrag[2], bfrag[4];
#pragma unroll
        for (int tm2 = 0; tm2 < 2; ++tm2)
          afrag[tm2] = *(const s16x8*)&Atile[tm2 * 16 + lr][lq * 8];
#pragma unroll
        for (int tn2 = 0; tn2 < 4; ++tn2)
          bfrag[tn2] = *(const s16x8*)&Btile[wv * 64 + tn2 * 16 + lr][lq * 8];
#pragma unroll
        for (int tm2 = 0; tm2 < 2; ++tm2)
#pragma unroll
          for (int tn2 = 0; tn2 < 4; ++tn2)
            acc[tm2][tn2] = __builtin_amdgcn_mfma_f32_16x16x32_bf16(
                afrag[tm2], bfrag[tn2], acc[tm2][tn2], 0, 0, 0);
      }
      __syncthreads();
    }
  }

  // epilogue: store + fused GroupNorm partial sums (group = co>>4 = wv*4+tn)
  {
    int lr = lane & 15, lq = lane >> 4;
#pragma unroll
    for (int tn = 0; tn < 4; ++tn) {
      int co = wv * 64 + tn * 16 + lr;
      float bco = bias[co];
      float* obase = convout + (size_t)(b * COUT + co) * HW + i * W + j0;
      float s = 0.f, q = 0.f;
#pragma unroll
      for (int tm = 0; tm < 2; ++tm)
#pragma unroll
        for (int r = 0; r < 4; ++r) {
          int m = tm * 16 + lq * 4 + r;
          float v = acc[tm][tn][r] + bco;
          obase[m] = v;
          s += v;
          q += v * v;
        }
#pragma unroll
      for (int off = 32; off > 0; off >>= 1) {
        s += __shfl_down(s, off, 64);
        q += __shfl_down(q, off, 64);
      }
      if (lane == 0) {
        atomicAdd(&gstat[(b * 16 + wv * 4 + tn) * 2 + 0], s);
        atomicAdd(&gstat[(b * 16 + wv * 4 + tn) * 2 + 1], q);
      }
    }
  }
}

// ---------------------------------------------------------------------------
// Kernel C: GroupNorm apply (stats already in gstat). grid 4096 x 256, float4.
// ---------------------------------------------------------------------------
__global__ __launch_bounds__(256) void gn_apply_kernel(
    const float* __restrict__ convout, const float* __restrict__ gstat,
    const float* __restrict__ gamma, const float* __restrict__ beta,
    float* __restrict__ out) {
  int vid = blockIdx.x * 256 + threadIdx.x;
  int e = vid * 4;
  int b = e >> 20;                 // 256*4096 elems per batch
  int c = (e >> 12) & 255;
  int g = c >> 4;
  float S = gstat[(b * 16 + g) * 2 + 0];
  float Q = gstat[(b * 16 + g) * 2 + 1];
  float mu = S * (1.f / 65536.f);
  float var = Q * (1.f / 65536.f) - mu * mu;
  float rs = rsqrtf(var + EPS);
  float a = rs * gamma[c];
  float bb = beta[c] - mu * a;
  float4 v = *(const float4*)(convout + e);
  float4 o = make_float4(v.x * a + bb, v.y * a + bb, v.z * a + bb, v.w * a + bb);
  *(float4*)(out + e) = o;
}

// ---------------------------------------------------------------------------
extern "C" void kernel_launch(void* const* d_in, const int* in_sizes, int n_in,
                              void* d_out, int out_size, void* d_ws, size_t ws_size,
                              hipStream_t stream) {
  const float* x      = (const float*)d_in[0];
  const float* w_off  = (const float*)d_in[1];
  const float* b_off  = (const float*)d_in[2];
  const float* weight = (const float*)d_in[3];
  const float* bias   = (const float*)d_in[4];
  const float* gamma  = (const float*)d_in[5];
  const float* beta   = (const float*)d_in[6];
  float* out = (float*)d_out;

  float* om      = (float*)d_ws;                        // 1.77 MB
  float* convout = om + (size_t)B_ * NOFF * HW;         // 16.8 MB
  unsigned short* wTT = (unsigned short*)(convout + (size_t)B_ * COUT * HW); // 1.18 MB
  unsigned short* wOT = wTT + (size_t)COUT * KC;        // 147 KB
  float* gstat = (float*)(wOT + (size_t)32 * KC);       // 512 B

  wprep_kernel<<<dim3(2304 + 288 + 1), dim3(256), 0, stream>>>(weight, w_off, wTT, wOT, gstat);
  offconv_mfma_kernel<<<dim3(512), dim3(256), 0, stream>>>(x, wOT, b_off, om);
  dcn_mfma_kernel<<<dim3(512), dim3(256), 0, stream>>>(x, om, wTT, bias, convout, gstat);
  gn_apply_kernel<<<dim3(4096), dim3(256), 0, stream>>>(convout, gstat, gamma, beta, out);
}

// Round 4
// 240.321 us; speedup vs baseline: 7.0357x; 1.7104x over previous
//
#include <hip/hip_runtime.h>
#include <math.h>

#define CIN   256
#define COUT  256
#define H     64
#define W     64
#define HW    4096
#define KK    9
#define KC    2304
#define NOFF  27
#define B_    4
#define EPS   1e-5f
#define MT    32        // pixels per block
#define APAD  72        // padded LDS row (ushorts): 144 B = 16B-aligned, 4-bank shift/row

typedef __attribute__((ext_vector_type(4))) float f32x4;
typedef __attribute__((ext_vector_type(8))) short s16x8;

static __device__ __forceinline__ unsigned short f2bf(float f) {
  unsigned u = __builtin_bit_cast(unsigned, f);
  u += 0x7FFF + ((u >> 16) & 1);
  return (unsigned short)(u >> 16);
}
static __device__ __forceinline__ float bflo(unsigned u) {
  return __builtin_bit_cast(float, u << 16);
}
static __device__ __forceinline__ float bfhi(unsigned u) {
  return __builtin_bit_cast(float, u & 0xffff0000u);
}
static __device__ __forceinline__ unsigned packbf(float lo, float hi) {
  unsigned ul = __builtin_bit_cast(unsigned, lo);
  unsigned uh = __builtin_bit_cast(unsigned, hi);
  ul += 0x7FFF + ((ul >> 16) & 1);
  uh += 0x7FFF + ((uh >> 16) & 1);
  return (ul >> 16) | (uh & 0xffff0000u);
}

// ---------------------------------------------------------------------------
// xprep: x NCHW f32 -> xT NHWC bf16. grid (b*64+y) = 256 blocks.
// ---------------------------------------------------------------------------
__global__ __launch_bounds__(256) void xprep_kernel(
    const float* __restrict__ x, unsigned short* __restrict__ xT) {
  __shared__ unsigned short tile[64][272];   // 544 B rows: 16B-aligned
  int bi = blockIdx.x;
  int b = bi >> 6, y = bi & 63;
  int t = threadIdx.x;
  const float* src = x + (size_t)b * CIN * HW + y * W;   // + c*HW + w
  for (int r = 0; r < 64; ++r) {
    int idx = r * 256 + t;
    int c = idx >> 6, w = idx & 63;
    tile[w][c] = f2bf(src[(size_t)c * HW + w]);
  }
  __syncthreads();
  unsigned short* dst = xT + ((size_t)(b * 64 + y) * 64) * 256;  // [w][c]
  for (int r = 0; r < 8; ++r) {
    int idx = r * 2048 + t * 8;
    int w = idx >> 8, c = idx & 255;
    *(uint4*)(dst + idx) = *(const uint4*)&tile[w][c];
  }
}

// ---------------------------------------------------------------------------
// wprep: chunk-major bf16 weights + gstat zero.
//  wB [kt][cc][co][col]  (col = c&63, cc = c>>6)   - main conv
//  wOB[kt][cc][oc][col]  oc<32 padded              - offset conv
// ---------------------------------------------------------------------------
__global__ __launch_bounds__(256) void wprep_kernel(
    const float* __restrict__ w, const float* __restrict__ w_off,
    unsigned short* __restrict__ wB, unsigned short* __restrict__ wOB,
    float* __restrict__ gstat) {
  int bi = blockIdx.x;
  if (bi < 2304) {
    int o = bi * 256 + threadIdx.x;       // (((kt*4+cc)*256+co)*64+col)
    int col = o & 63;
    int co  = (o >> 6) & 255;
    int cc  = (o >> 14) & 3;
    int kt  = o >> 16;
    int c = cc * 64 + col;
    wB[o] = f2bf(w[(co * 256 + c) * 9 + kt]);
  } else if (bi < 2304 + 288) {
    int o = (bi - 2304) * 256 + threadIdx.x;  // (((kt*4+cc)*32+oc)*64+col)
    int col = o & 63;
    int oc  = (o >> 6) & 31;
    int cc  = (o >> 11) & 3;
    int kt  = o >> 13;
    int c = cc * 64 + col;
    wOB[o] = (oc < NOFF) ? f2bf(w_off[(oc * 256 + c) * 9 + kt]) : (unsigned short)0;
  } else {
    if (threadIdx.x < 128) gstat[threadIdx.x] = 0.f;
  }
}

// ---------------------------------------------------------------------------
// offconv: bf16 MFMA GEMM, M=16384, N=32(pad), K=2304. A = shifted NHWC rows.
// Block 32 px x 32 oc, 4 waves (wave tile 16x16). grid 512.
// ---------------------------------------------------------------------------
__global__ __launch_bounds__(256, 2) void offconv_mfma_kernel(
    const unsigned short* __restrict__ xT, const unsigned short* __restrict__ wOB,
    const float* __restrict__ b_off, float* __restrict__ om) {
  __shared__ unsigned short At[MT][APAD];
  __shared__ unsigned short Bt[32][APAD];
  int bi = blockIdx.x;
  int b = bi >> 7, i = (bi >> 1) & 63, j0 = (bi & 1) * MT;
  int t = threadIdx.x, lane = t & 63, wv = t >> 6;
  int tm = wv & 1, tn = wv >> 1;
  int sp = t >> 3, oc8 = t & 7;
  const unsigned short* xb = xT + (size_t)b * (HW * 256);
  f32x4 acc = {};

  for (int kt = 0; kt < KK; ++kt) {
    int ky = kt / 3, kx = kt % 3;
    int yy = i - 1 + ky;
    int xx = j0 + sp - 1 + kx;
    bool ok = ((unsigned)yy < 64u) && ((unsigned)xx < 64u);
    const unsigned short* asrc = xb + ((ok ? yy * 64 + xx : 0) << 8) + oc8 * 8;
    for (int cc = 0; cc < 4; ++cc) {
      { // stage B: 256 granules of 16B
        const uint4* src = (const uint4*)(wOB + (kt * 4 + cc) * 2048);
        *(uint4*)&Bt[t >> 3][(t & 7) * 8] = src[t];
      }
      { // stage A: direct im2col
        uint4 v = uint4{0, 0, 0, 0};
        if (ok) v = *(const uint4*)(asrc + cc * 64);
        *(uint4*)&At[sp][oc8 * 8] = v;
      }
      __syncthreads();
      {
        int lr = lane & 15, lq = lane >> 4;
#pragma unroll
        for (int kh = 0; kh < 2; ++kh) {
          s16x8 a  = *(const s16x8*)&At[tm * 16 + lr][kh * 32 + lq * 8];
          s16x8 bb = *(const s16x8*)&Bt[tn * 16 + lr][kh * 32 + lq * 8];
          acc = __builtin_amdgcn_mfma_f32_16x16x32_bf16(a, bb, acc, 0, 0, 0);
        }
      }
      __syncthreads();
    }
  }
  int lr = lane & 15, lq = lane >> 4;
  int oc = tn * 16 + lr;
  if (oc < NOFF) {
    float bo = b_off[oc];
    float* ob = om + (size_t)(b * NOFF + oc) * HW + i * 64 + j0 + tm * 16;
#pragma unroll
    for (int r = 0; r < 4; ++r) ob[lq * 4 + r] = acc[r] + bo;
  }
}

// ---------------------------------------------------------------------------
// dcn: deformable conv bf16 MFMA + fused GN partial stats. NHWC gather.
// Block 32 px x 256 co, 4 waves (wave tile 32x64). K-chunk 64. grid 512.
// ---------------------------------------------------------------------------
__global__ __launch_bounds__(256, 2) void dcn_mfma_kernel(
    const unsigned short* __restrict__ xT, const float* __restrict__ om,
    const unsigned short* __restrict__ wB, const float* __restrict__ bias,
    unsigned short* __restrict__ convout, float* __restrict__ gstat) {
  __shared__ unsigned short At[MT][APAD];
  __shared__ unsigned short Bt[256][APAD];
  int bi = blockIdx.x;
  int b = bi >> 7, i = (bi >> 1) & 63, j0 = (bi & 1) * MT;
  int t = threadIdx.x, lane = t & 63, wv = t >> 6;
  int sp = t >> 3, oc8 = t & 7;
  const unsigned short* xb = xT + (size_t)b * (HW * 256);
  const float* omb = om + (size_t)b * NOFF * HW;
  f32x4 acc[2][4] = {};
  int pix = i * 64 + j0 + sp;

  for (int kt = 0; kt < KK; ++kt) {
    // per-lane tap data for pixel sp (8 lanes redundantly, registers only)
    float offy = omb[kt * HW + pix];
    float offx = omb[(9 + kt) * HW + pix];
    float mval = omb[(18 + kt) * HW + pix];
    float mask = 1.f / (1.f + __expf(-mval));
    float py = (float)(i - 1 + kt / 3) + offy;
    float px = (float)(j0 + sp - 1 + kt % 3) + offx;
    float y0f = floorf(py), x0f = floorf(px);
    float wy1 = py - y0f, wx1 = px - x0f;
    int y0 = (int)y0f, x0 = (int)x0f;
    bool y0ok = (unsigned)y0 < 64u, y1ok = (unsigned)(y0 + 1) < 64u;
    bool x0ok = (unsigned)x0 < 64u, x1ok = (unsigned)(x0 + 1) < 64u;
    float w00 = (1.f - wy1) * (1.f - wx1) * mask * (float)(y0ok && x0ok);
    float w01 = (1.f - wy1) * wx1 * mask * (float)(y0ok && x1ok);
    float w10 = wy1 * (1.f - wx1) * mask * (float)(y1ok && x0ok);
    float w11 = wy1 * wx1 * mask * (float)(y1ok && x1ok);
    int y0c = min(max(y0, 0), 63), y1c = min(max(y0 + 1, 0), 63);
    int x0c = min(max(x0, 0), 63), x1c = min(max(x0 + 1, 0), 63);
    const unsigned short* p00 = xb + ((y0c * 64 + x0c) << 8) + oc8 * 8;
    const unsigned short* p01 = xb + ((y0c * 64 + x1c) << 8) + oc8 * 8;
    const unsigned short* p10 = xb + ((y1c * 64 + x0c) << 8) + oc8 * 8;
    const unsigned short* p11 = xb + ((y1c * 64 + x1c) << 8) + oc8 * 8;

    for (int cc = 0; cc < 4; ++cc) {
      int coff = cc * 64;
      { // stage B: 2048 granules, 8 per thread, coalesced
        const uint4* src = (const uint4*)(wB + ((size_t)(kt * 4 + cc) << 14));
#pragma unroll
        for (int q = 0; q < 8; ++q) {
          int gi = q * 256 + t;
          *(uint4*)&Bt[gi >> 3][(gi & 7) * 8] = src[gi];
        }
      }
      { // stage A: bilinear over 8 contiguous channels
        uint4 v00 = *(const uint4*)(p00 + coff);
        uint4 v01 = *(const uint4*)(p01 + coff);
        uint4 v10 = *(const uint4*)(p10 + coff);
        uint4 v11 = *(const uint4*)(p11 + coff);
        const unsigned* a00 = (const unsigned*)&v00;
        const unsigned* a01 = (const unsigned*)&v01;
        const unsigned* a10 = (const unsigned*)&v10;
        const unsigned* a11 = (const unsigned*)&v11;
        uint4 res;
        unsigned* rr = (unsigned*)&res;
#pragma unroll
        for (int q = 0; q < 4; ++q) {
          float lo = w00 * bflo(a00[q]) + w01 * bflo(a01[q]) +
                     w10 * bflo(a10[q]) + w11 * bflo(a11[q]);
          float hi = w00 * bfhi(a00[q]) + w01 * bfhi(a01[q]) +
                     w10 * bfhi(a10[q]) + w11 * bfhi(a11[q]);
          rr[q] = packbf(lo, hi);
        }
        *(uint4*)&At[sp][oc8 * 8] = res;
      }
      __syncthreads();
      {
        int lr = lane & 15, lq = lane >> 4;
        s16x8 af[2][2], bf[4][2];
#pragma unroll
        for (int tm = 0; tm < 2; ++tm)
#pragma unroll
          for (int kh = 0; kh < 2; ++kh)
            af[tm][kh] = *(const s16x8*)&At[tm * 16 + lr][kh * 32 + lq * 8];
#pragma unroll
        for (int tn = 0; tn < 4; ++tn)
#pragma unroll
          for (int kh = 0; kh < 2; ++kh)
            bf[tn][kh] = *(const s16x8*)&Bt[wv * 64 + tn * 16 + lr][kh * 32 + lq * 8];
#pragma unroll
        for (int kh = 0; kh < 2; ++kh)
#pragma unroll
          for (int tm = 0; tm < 2; ++tm)
#pragma unroll
            for (int tn = 0; tn < 4; ++tn)
              acc[tm][tn] = __builtin_amdgcn_mfma_f32_16x16x32_bf16(
                  af[tm][kh], bf[tn][kh], acc[tm][tn], 0, 0, 0);
      }
      __syncthreads();
    }
  }

  // epilogue: bf16 store + fused GroupNorm partial sums (group = wv*4+tn)
  {
    int lr = lane & 15, lq = lane >> 4;
#pragma unroll
    for (int tn = 0; tn < 4; ++tn) {
      int co = wv * 64 + tn * 16 + lr;
      float bco = bias[co];
      unsigned short* cvb = convout + (size_t)(b * COUT + co) * HW + i * 64 + j0;
      float s = 0.f, q = 0.f;
#pragma unroll
      for (int tm = 0; tm < 2; ++tm) {
        ushort4 st;
#pragma unroll
        for (int r = 0; r < 4; ++r) {
          float v = acc[tm][tn][r] + bco;
          s += v;
          q += v * v;
          ((unsigned short*)&st)[r] = f2bf(v);
        }
        *(ushort4*)(cvb + tm * 16 + lq * 4) = st;
      }
#pragma unroll
      for (int off = 32; off > 0; off >>= 1) {
        s += __shfl_down(s, off, 64);
        q += __shfl_down(q, off, 64);
      }
      if (lane == 0) {
        atomicAdd(&gstat[(b * 16 + wv * 4 + tn) * 2 + 0], s);
        atomicAdd(&gstat[(b * 16 + wv * 4 + tn) * 2 + 1], q);
      }
    }
  }
}

// ---------------------------------------------------------------------------
// gn_apply: normalize bf16 convout -> f32 out. grid 2048 x 256, 8 elems/thread.
// ---------------------------------------------------------------------------
__global__ __launch_bounds__(256) void gn_apply_kernel(
    const unsigned short* __restrict__ convout, const float* __restrict__ gstat,
    const float* __restrict__ gamma, const float* __restrict__ beta,
    float* __restrict__ out) {
  int vid = blockIdx.x * 256 + threadIdx.x;
  int e = vid * 8;
  int b = e >> 20;                 // 256*4096 per batch
  int c = (e >> 12) & 255;
  int g = c >> 4;
  float S = gstat[(b * 16 + g) * 2 + 0];
  float Q = gstat[(b * 16 + g) * 2 + 1];
  float mu = S * (1.f / 65536.f);
  float var = Q * (1.f / 65536.f) - mu * mu;
  float rs = rsqrtf(var + EPS);
  float a = rs * gamma[c];
  float bb = beta[c] - mu * a;
  uint4 v = *(const uint4*)(convout + e);
  const unsigned* u = (const unsigned*)&v;
  float4 o0, o1;
  o0.x = bflo(u[0]) * a + bb;  o0.y = bfhi(u[0]) * a + bb;
  o0.z = bflo(u[1]) * a + bb;  o0.w = bfhi(u[1]) * a + bb;
  o1.x = bflo(u[2]) * a + bb;  o1.y = bfhi(u[2]) * a + bb;
  o1.z = bflo(u[3]) * a + bb;  o1.w = bfhi(u[3]) * a + bb;
  *(float4*)(out + e) = o0;
  *(float4*)(out + e + 4) = o1;
}

// ---------------------------------------------------------------------------
extern "C" void kernel_launch(void* const* d_in, const int* in_sizes, int n_in,
                              void* d_out, int out_size, void* d_ws, size_t ws_size,
                              hipStream_t stream) {
  const float* x      = (const float*)d_in[0];
  const float* w_off  = (const float*)d_in[1];
  const float* b_off  = (const float*)d_in[2];
  const float* weight = (const float*)d_in[3];
  const float* bias   = (const float*)d_in[4];
  const float* gamma  = (const float*)d_in[5];
  const float* beta   = (const float*)d_in[6];
  float* out = (float*)d_out;

  float* om = (float*)d_ws;                                   // 1.77 MB
  unsigned short* xT  = (unsigned short*)(om + (size_t)B_ * NOFF * HW);   // 8.39 MB
  unsigned short* cvt = xT + (size_t)B_ * HW * 256;           // convout bf16, 8.39 MB
  unsigned short* wB  = cvt + (size_t)B_ * COUT * HW;         // 1.18 MB
  unsigned short* wOB = wB + (size_t)COUT * KC;               // 147 KB
  float* gstat = (float*)(wOB + (size_t)32 * KC);             // 512 B

  xprep_kernel<<<dim3(B_ * 64), dim3(256), 0, stream>>>(x, xT);
  wprep_kernel<<<dim3(2304 + 288 + 1), dim3(256), 0, stream>>>(weight, w_off, wB, wOB, gstat);
  offconv_mfma_kernel<<<dim3(512), dim3(256), 0, stream>>>(xT, wOB, b_off, om);
  dcn_mfma_kernel<<<dim3(512), dim3(256), 0, stream>>>(xT, om, wB, bias, cvt, gstat);
  gn_apply_kernel<<<dim3(2048), dim3(256), 0, stream>>>(cvt, gstat, gamma, beta, out);
}

// Round 5
// 236.906 us; speedup vs baseline: 7.1371x; 1.0144x over previous
//
#include <hip/hip_runtime.h>
#include <math.h>

#define CIN   256
#define COUT  256
#define H     64
#define W     64
#define HW    4096
#define KK    9
#define KC    2304
#define NOFF  27
#define B_    4
#define EPS   1e-5f
#define MT    32        // pixels per dcn block
#define APAD  72        // LDS A row pitch (ushorts): 144 B, 2-way-free bank shift

typedef __attribute__((ext_vector_type(4))) float f32x4;
typedef __attribute__((ext_vector_type(8))) short s16x8;

static __device__ __forceinline__ unsigned short f2bf(float f) {
  unsigned u = __builtin_bit_cast(unsigned, f);
  u += 0x7FFF + ((u >> 16) & 1);
  return (unsigned short)(u >> 16);
}
static __device__ __forceinline__ float bflo(unsigned u) {
  return __builtin_bit_cast(float, u << 16);
}
static __device__ __forceinline__ float bfhi(unsigned u) {
  return __builtin_bit_cast(float, u & 0xffff0000u);
}
static __device__ __forceinline__ unsigned packbf(float lo, float hi) {
  unsigned ul = __builtin_bit_cast(unsigned, lo);
  unsigned uh = __builtin_bit_cast(unsigned, hi);
  ul += 0x7FFF + ((ul >> 16) & 1);
  uh += 0x7FFF + ((uh >> 16) & 1);
  return (ul >> 16) | (uh & 0xffff0000u);
}

// ---------------------------------------------------------------------------
// xprep: x NCHW f32 -> xT NHWC bf16. grid 256.
// ---------------------------------------------------------------------------
__global__ __launch_bounds__(256) void xprep_kernel(
    const float* __restrict__ x, unsigned short* __restrict__ xT) {
  __shared__ unsigned short tile[64][272];
  int bi = blockIdx.x;
  int b = bi >> 6, y = bi & 63;
  int t = threadIdx.x;
  const float* src = x + (size_t)b * CIN * HW + y * W;
  for (int r = 0; r < 64; ++r) {
    int idx = r * 256 + t;
    int c = idx >> 6, w = idx & 63;
    tile[w][c] = f2bf(src[(size_t)c * HW + w]);
  }
  __syncthreads();
  unsigned short* dst = xT + ((size_t)(b * 64 + y) * 64) * 256;
  for (int r = 0; r < 8; ++r) {
    int idx = r * 2048 + t * 8;
    int w = idx >> 8, c = idx & 255;
    *(uint4*)(dst + idx) = *(const uint4*)&tile[w][c];
  }
}

// ---------------------------------------------------------------------------
// wprep: weights -> MFMA-B-fragment order bf16.
//  wBf : packet p = (k2*16 + tn)*64 + lane, 8 bf16/packet:
//        element j: co = tn*16 + (lane&15); k' = k2*32 + (lane>>4)*8 + j
//        (k' = tap*256 + c). 288 blocks.
//  wOBf: same with tn in [0,2), oc>=27 zero.  36 blocks.
//  last block zeroes gstat.
// ---------------------------------------------------------------------------
__global__ __launch_bounds__(256) void wprep_kernel(
    const float* __restrict__ w, const float* __restrict__ w_off,
    unsigned short* __restrict__ wBf, unsigned short* __restrict__ wOBf,
    float* __restrict__ gstat) {
  int bi = blockIdx.x;
  if (bi < 288) {
    int pkt = bi * 256 + threadIdx.x;      // [0, 73728)
    int lane = pkt & 63;
    int tn = (pkt >> 6) & 15;
    int k2 = pkt >> 10;
    int co = tn * 16 + (lane & 15);
    int kb = k2 * 32 + (lane >> 4) * 8;
    unsigned short v[8];
#pragma unroll
    for (int j = 0; j < 8; ++j) {
      int kk = kb + j;
      int kt = kk >> 8, c = kk & 255;
      v[j] = f2bf(w[(co * 256 + c) * 9 + kt]);
    }
    *(uint4*)&wBf[(size_t)pkt * 8] = *(const uint4*)v;
  } else if (bi < 288 + 36) {
    int pkt = (bi - 288) * 256 + threadIdx.x;  // [0, 9216)
    int lane = pkt & 63;
    int tn = (pkt >> 6) & 1;
    int k2 = pkt >> 7;
    int oc = tn * 16 + (lane & 15);
    int kb = k2 * 32 + (lane >> 4) * 8;
    unsigned short v[8];
#pragma unroll
    for (int j = 0; j < 8; ++j) {
      int kk = kb + j;
      int kt = kk >> 8, c = kk & 255;
      v[j] = (oc < NOFF) ? f2bf(w_off[(oc * 256 + c) * 9 + kt]) : (unsigned short)0;
    }
    *(uint4*)&wOBf[(size_t)pkt * 8] = *(const uint4*)v;
  } else {
    if (threadIdx.x < 128) gstat[threadIdx.x] = 0.f;
  }
}

// ---------------------------------------------------------------------------
// offconv: no LDS, no barriers. Block = 64 px (one image row), 4 waves;
// wave w: px [w*16, w*16+16), oc tiles 0..1 (27 of 32). A frags direct from
// NHWC xT, B frags direct from wOBf (fragment order). grid 256.
// ---------------------------------------------------------------------------
__global__ __launch_bounds__(256) void offconv_mfma_kernel(
    const unsigned short* __restrict__ xT, const unsigned short* __restrict__ wOBf,
    const float* __restrict__ b_off, float* __restrict__ om) {
  int bi = blockIdx.x;
  int b = bi >> 6, i = bi & 63;
  int t = threadIdx.x, lane = t & 63, wv = t >> 6;
  int lr = lane & 15, lq = lane >> 4;
  int p = wv * 16 + lr;                     // pixel column
  const unsigned short* xb = xT + (size_t)b * (HW * 256);
  f32x4 acc[2] = {};

  for (int kt = 0; kt < KK; ++kt) {
    int ky = kt / 3, kx = kt % 3;
    int yy = i - 1 + ky, xx = p - 1 + kx;
    bool ok = ((unsigned)yy < 64u) && ((unsigned)xx < 64u);
    const unsigned short* ap = xb + ((ok ? yy * 64 + xx : 0) << 8) + lq * 8;
#pragma unroll
    for (int c8 = 0; c8 < 8; ++c8) {
      uint4 av = uint4{0, 0, 0, 0};
      if (ok) av = *(const uint4*)(ap + c8 * 32);
      int k2 = kt * 8 + c8;
      s16x8 a = __builtin_bit_cast(s16x8, av);
      s16x8 b0 = *(const s16x8*)(wOBf + ((((k2 * 2 + 0) << 6) | lane) << 3));
      s16x8 b1 = *(const s16x8*)(wOBf + ((((k2 * 2 + 1) << 6) | lane) << 3));
      acc[0] = __builtin_amdgcn_mfma_f32_16x16x32_bf16(a, b0, acc[0], 0, 0, 0);
      acc[1] = __builtin_amdgcn_mfma_f32_16x16x32_bf16(a, b1, acc[1], 0, 0, 0);
    }
  }
#pragma unroll
  for (int tn = 0; tn < 2; ++tn) {
    int oc = tn * 16 + lr;
    if (oc < NOFF) {
      float bo = b_off[oc];
      float* ob = om + (size_t)(b * NOFF + oc) * HW + i * 64 + wv * 16;
#pragma unroll
      for (int r = 0; r < 4; ++r) ob[lq * 4 + r] = acc[tn][r] + bo;
    }
  }
}

// ---------------------------------------------------------------------------
// dcn: A via LDS (shared bilinear samples), B direct-from-L2 fragment loads.
// Double-buffered corner/B registers; prefetch issued after 2nd barrier so
// MFMA + next sampling covers L2 latency. Block 32px x 256co, 4 waves,
// K-chunk 64 (36 iters). grid 512.
// ---------------------------------------------------------------------------
__global__ __launch_bounds__(256, 2) void dcn_mfma_kernel(
    const unsigned short* __restrict__ xT, const float* __restrict__ om,
    const unsigned short* __restrict__ wBf, const float* __restrict__ bias,
    unsigned short* __restrict__ convout, float* __restrict__ gstat) {
  __shared__ unsigned short At[MT][APAD];
  __shared__ float tapw[MT][KK][4];
  __shared__ int   taps[MT][KK][4];   // base*256, dxA, dyA, pad

  int bi = blockIdx.x;
  int b = bi >> 7, i = (bi >> 1) & 63, j0 = (bi & 1) * MT;
  int t = threadIdx.x, lane = t & 63, wv = t >> 6;
  int sp = t >> 3, oc8 = t & 7;
  int lr = lane & 15, lq = lane >> 4;
  const unsigned short* xb = xT + (size_t)b * (HW * 256);
  const float* omb = om + (size_t)b * NOFF * HW;

  // --- tap tables (once) ---
  for (int idx = t; idx < MT * KK; idx += 256) {
    int p = idx / KK, k = idx % KK;
    int pix = i * 64 + j0 + p;
    float offy = omb[k * HW + pix];
    float offx = omb[(9 + k) * HW + pix];
    float mval = omb[(18 + k) * HW + pix];
    float mask = 1.f / (1.f + __expf(-mval));
    float py = (float)(i - 1 + k / 3) + offy;
    float px = (float)(j0 + p - 1 + k % 3) + offx;
    float y0f = floorf(py), x0f = floorf(px);
    float wy1 = py - y0f, wx1 = px - x0f;
    int y0 = (int)y0f, x0 = (int)x0f;
    bool y0ok = (unsigned)y0 < 64u, y1ok = (unsigned)(y0 + 1) < 64u;
    bool x0ok = (unsigned)x0 < 64u, x1ok = (unsigned)(x0 + 1) < 64u;
    tapw[p][k][0] = (1.f - wy1) * (1.f - wx1) * mask * (float)(y0ok && x0ok);
    tapw[p][k][1] = (1.f - wy1) * wx1 * mask * (float)(y0ok && x1ok);
    tapw[p][k][2] = wy1 * (1.f - wx1) * mask * (float)(y1ok && x0ok);
    tapw[p][k][3] = wy1 * wx1 * mask * (float)(y1ok && x1ok);
    int y0c = min(max(y0, 0), 63), y1c = min(max(y0 + 1, 0), 63);
    int x0c = min(max(x0, 0), 63), x1c = min(max(x0 + 1, 0), 63);
    taps[p][k][0] = (y0c * 64 + x0c) * 256;
    taps[p][k][1] = (x1c - x0c) * 256;
    taps[p][k][2] = (y1c - y0c) * 64 * 256;
    taps[p][k][3] = 0;
  }
  __syncthreads();

  f32x4 acc[2][4] = {};
  uint4 cor[2][4];
  s16x8 Bf[2][8];
  float cw00, cw01, cw10, cw11;
  int cbase, cdx, cdy;

  // tap 0 regs
  {
    f32x4 tw = *(const f32x4*)&tapw[sp][0][0];
    cw00 = tw[0]; cw01 = tw[1]; cw10 = tw[2]; cw11 = tw[3];
    int4 ts = *(const int4*)&taps[sp][0][0];
    cbase = ts.x; cdx = ts.y; cdy = ts.z;
  }
  // prefetch chunk 0
  {
    int a = cbase + oc8 * 8;
    cor[0][0] = *(const uint4*)(xb + a);
    cor[0][1] = *(const uint4*)(xb + a + cdx);
    cor[0][2] = *(const uint4*)(xb + a + cdy);
    cor[0][3] = *(const uint4*)(xb + a + cdy + cdx);
#pragma unroll
    for (int tn2 = 0; tn2 < 4; ++tn2)
#pragma unroll
      for (int kh = 0; kh < 2; ++kh)
        Bf[0][tn2 * 2 + kh] = *(const s16x8*)(
            wBf + ((((kh * 16 + wv * 4 + tn2) << 6) | lane) << 3));
  }

#pragma unroll 2
  for (int chunk = 0; chunk < 36; ++chunk) {
    int cur = chunk & 1, nxt = cur ^ 1;
    // 1. bilinear sample from prefetched corners (weights match this chunk's tap)
    uint4 res;
    {
      const unsigned* a00 = (const unsigned*)&cor[cur][0];
      const unsigned* a01 = (const unsigned*)&cor[cur][1];
      const unsigned* a10 = (const unsigned*)&cor[cur][2];
      const unsigned* a11 = (const unsigned*)&cor[cur][3];
      unsigned* rr = (unsigned*)&res;
#pragma unroll
      for (int q = 0; q < 4; ++q) {
        float lo = cw00 * bflo(a00[q]) + cw01 * bflo(a01[q]) +
                   cw10 * bflo(a10[q]) + cw11 * bflo(a11[q]);
        float hi = cw00 * bfhi(a00[q]) + cw01 * bfhi(a01[q]) +
                   cw10 * bfhi(a10[q]) + cw11 * bfhi(a11[q]);
        rr[q] = packbf(lo, hi);
      }
    }
    __syncthreads();                 // prev chunk's A consumers done
    *(uint4*)&At[sp][oc8 * 8] = res;
    int chn = chunk + 1;
    if (chn < 36 && (chn & 3) == 0) {  // tap rollover: new weights+addresses
      int ktn = chn >> 2;
      f32x4 tw = *(const f32x4*)&tapw[sp][ktn][0];
      cw00 = tw[0]; cw01 = tw[1]; cw10 = tw[2]; cw11 = tw[3];
      int4 ts = *(const int4*)&taps[sp][ktn][0];
      cbase = ts.x; cdx = ts.y; cdy = ts.z;
    }
    __syncthreads();                 // At visible
    // 2. prefetch next chunk (issued after barrier: stays in flight over MFMA)
    if (chn < 36) {
      int a = cbase + ((chn & 3) << 6) + oc8 * 8;
      cor[nxt][0] = *(const uint4*)(xb + a);
      cor[nxt][1] = *(const uint4*)(xb + a + cdx);
      cor[nxt][2] = *(const uint4*)(xb + a + cdy);
      cor[nxt][3] = *(const uint4*)(xb + a + cdy + cdx);
      int k2b = chn * 2;
#pragma unroll
      for (int tn2 = 0; tn2 < 4; ++tn2)
#pragma unroll
        for (int kh = 0; kh < 2; ++kh)
          Bf[nxt][tn2 * 2 + kh] = *(const s16x8*)(
              wBf + (((((k2b + kh) * 16 + wv * 4 + tn2) << 6) | lane) << 3));
    }
    // 3. A frags + MFMA
    {
      s16x8 af[2][2];
#pragma unroll
      for (int tm = 0; tm < 2; ++tm)
#pragma unroll
        for (int kh = 0; kh < 2; ++kh)
          af[tm][kh] = *(const s16x8*)&At[tm * 16 + lr][kh * 32 + lq * 8];
#pragma unroll
      for (int kh = 0; kh < 2; ++kh)
#pragma unroll
        for (int tm = 0; tm < 2; ++tm)
#pragma unroll
          for (int tn2 = 0; tn2 < 4; ++tn2)
            acc[tm][tn2] = __builtin_amdgcn_mfma_f32_16x16x32_bf16(
                af[tm][kh], Bf[cur][tn2 * 2 + kh], acc[tm][tn2], 0, 0, 0);
    }
  }

  // epilogue: bias + bf16 store + fused GN partial sums (group = wv*4+tn)
  {
#pragma unroll
    for (int tn = 0; tn < 4; ++tn) {
      int co = wv * 64 + tn * 16 + lr;
      float bco = bias[co];
      unsigned short* cvb = convout + (size_t)(b * COUT + co) * HW + i * 64 + j0;
      float s = 0.f, q = 0.f;
#pragma unroll
      for (int tm = 0; tm < 2; ++tm) {
        ushort4 st;
#pragma unroll
        for (int r = 0; r < 4; ++r) {
          float v = acc[tm][tn][r] + bco;
          s += v;
          q += v * v;
          ((unsigned short*)&st)[r] = f2bf(v);
        }
        *(ushort4*)(cvb + tm * 16 + lq * 4) = st;
      }
#pragma unroll
      for (int off = 32; off > 0; off >>= 1) {
        s += __shfl_down(s, off, 64);
        q += __shfl_down(q, off, 64);
      }
      if (lane == 0) {
        atomicAdd(&gstat[(b * 16 + wv * 4 + tn) * 2 + 0], s);
        atomicAdd(&gstat[(b * 16 + wv * 4 + tn) * 2 + 1], q);
      }
    }
  }
}

// ---------------------------------------------------------------------------
// gn_apply: normalize bf16 convout -> f32 out. grid 2048.
// ---------------------------------------------------------------------------
__global__ __launch_bounds__(256) void gn_apply_kernel(
    const unsigned short* __restrict__ convout, const float* __restrict__ gstat,
    const float* __restrict__ gamma, const float* __restrict__ beta,
    float* __restrict__ out) {
  int vid = blockIdx.x * 256 + threadIdx.x;
  int e = vid * 8;
  int b = e >> 20;
  int c = (e >> 12) & 255;
  int g = c >> 4;
  float S = gstat[(b * 16 + g) * 2 + 0];
  float Q = gstat[(b * 16 + g) * 2 + 1];
  float mu = S * (1.f / 65536.f);
  float var = Q * (1.f / 65536.f) - mu * mu;
  float rs = rsqrtf(var + EPS);
  float a = rs * gamma[c];
  float bb = beta[c] - mu * a;
  uint4 v = *(const uint4*)(convout + e);
  const unsigned* u = (const unsigned*)&v;
  float4 o0, o1;
  o0.x = bflo(u[0]) * a + bb;  o0.y = bfhi(u[0]) * a + bb;
  o0.z = bflo(u[1]) * a + bb;  o0.w = bfhi(u[1]) * a + bb;
  o1.x = bflo(u[2]) * a + bb;  o1.y = bfhi(u[2]) * a + bb;
  o1.z = bflo(u[3]) * a + bb;  o1.w = bfhi(u[3]) * a + bb;
  *(float4*)(out + e) = o0;
  *(float4*)(out + e + 4) = o1;
}

// ---------------------------------------------------------------------------
extern "C" void kernel_launch(void* const* d_in, const int* in_sizes, int n_in,
                              void* d_out, int out_size, void* d_ws, size_t ws_size,
                              hipStream_t stream) {
  const float* x      = (const float*)d_in[0];
  const float* w_off  = (const float*)d_in[1];
  const float* b_off  = (const float*)d_in[2];
  const float* weight = (const float*)d_in[3];
  const float* bias   = (const float*)d_in[4];
  const float* gamma  = (const float*)d_in[5];
  const float* beta   = (const float*)d_in[6];
  float* out = (float*)d_out;

  float* om = (float*)d_ws;                                   // 1.77 MB
  unsigned short* xT  = (unsigned short*)(om + (size_t)B_ * NOFF * HW);   // 8.39 MB
  unsigned short* cvt = xT + (size_t)B_ * HW * 256;           // 8.39 MB
  unsigned short* wBf = cvt + (size_t)B_ * COUT * HW;         // 1.18 MB
  unsigned short* wOBf = wBf + (size_t)COUT * KC;             // 147 KB
  float* gstat = (float*)(wOBf + (size_t)32 * KC);            // 512 B

  xprep_kernel<<<dim3(B_ * 64), dim3(256), 0, stream>>>(x, xT);
  wprep_kernel<<<dim3(288 + 36 + 1), dim3(256), 0, stream>>>(weight, w_off, wBf, wOBf, gstat);
  offconv_mfma_kernel<<<dim3(B_ * 64), dim3(256), 0, stream>>>(xT, wOBf, b_off, om);
  dcn_mfma_kernel<<<dim3(512), dim3(256), 0, stream>>>(xT, om, wBf, bias, cvt, gstat);
  gn_apply_kernel<<<dim3(2048), dim3(256), 0, stream>>>(cvt, gstat, gamma, beta, out);
}

// Round 6
// 220.227 us; speedup vs baseline: 7.6777x; 1.0757x over previous
//
#include <hip/hip_runtime.h>
#include <math.h>

#define CIN   256
#define COUT  256
#define H     64
#define W     64
#define HW    4096
#define KK    9
#define KC    2304
#define NOFF  27
#define B_    4
#define EPS   1e-5f
#define OM3S  (B_ * NOFF * HW)   // 442368 floats per partial buffer

typedef __attribute__((ext_vector_type(4))) float f32x4;
typedef __attribute__((ext_vector_type(8))) short s16x8;

static __device__ __forceinline__ unsigned short f2bf(float f) {
  unsigned u = __builtin_bit_cast(unsigned, f);
  u += 0x7FFF + ((u >> 16) & 1);
  return (unsigned short)(u >> 16);
}
static __device__ __forceinline__ float bflo(unsigned u) {
  return __builtin_bit_cast(float, u << 16);
}
static __device__ __forceinline__ float bfhi(unsigned u) {
  return __builtin_bit_cast(float, u & 0xffff0000u);
}
static __device__ __forceinline__ unsigned packbf(float lo, float hi) {
  unsigned ul = __builtin_bit_cast(unsigned, lo);
  unsigned uh = __builtin_bit_cast(unsigned, hi);
  ul += 0x7FFF + ((ul >> 16) & 1);
  uh += 0x7FFF + ((uh >> 16) & 1);
  return (ul >> 16) | (uh & 0xffff0000u);
}
static __device__ __forceinline__ void gl2lds16(const void* g, void* l) {
  __builtin_amdgcn_global_load_lds(
      (const __attribute__((address_space(1))) unsigned int*)g,
      (__attribute__((address_space(3))) unsigned int*)l, 16, 0, 0);
}

// ---------------------------------------------------------------------------
// xprep: x NCHW f32 -> xT NHWC bf16. grid 256.
// ---------------------------------------------------------------------------
__global__ __launch_bounds__(256) void xprep_kernel(
    const float* __restrict__ x, unsigned short* __restrict__ xT) {
  __shared__ unsigned short tile[64][272];
  int bi = blockIdx.x;
  int b = bi >> 6, y = bi & 63;
  int t = threadIdx.x;
  const float* src = x + (size_t)b * CIN * HW + y * W;
  for (int r = 0; r < 64; ++r) {
    int idx = r * 256 + t;
    int c = idx >> 6, w = idx & 63;
    tile[w][c] = f2bf(src[(size_t)c * HW + w]);
  }
  __syncthreads();
  unsigned short* dst = xT + ((size_t)(b * 64 + y) * 64) * 256;
  for (int r = 0; r < 8; ++r) {
    int idx = r * 2048 + t * 8;
    int w = idx >> 8, c = idx & 255;
    *(uint4*)(dst + idx) = *(const uint4*)&tile[w][c];
  }
}

// ---------------------------------------------------------------------------
// wprep:
//  blocks [0,2304):     wTT[co][k'] co-major, k' = kt*256 + c  (GEMM B)
//  blocks [2304,2340):  wOBf fragment-order for offconv
//  block 2340:          zero gstat
// ---------------------------------------------------------------------------
__global__ __launch_bounds__(256) void wprep_kernel(
    const float* __restrict__ w, const float* __restrict__ w_off,
    unsigned short* __restrict__ wTT, unsigned short* __restrict__ wOBf,
    float* __restrict__ gstat) {
  int bi = blockIdx.x;
  if (bi < 2304) {
    int idx = bi * 256 + threadIdx.x;      // co*2304 + kt*256 + c
    int c  = idx & 255;
    int kt = (idx >> 8) % 9;
    int co = idx / KC;
    wTT[idx] = f2bf(w[(co * 256 + c) * 9 + kt]);
  } else if (bi < 2340) {
    int pkt = (bi - 2304) * 256 + threadIdx.x;  // [0, 9216)
    int lane = pkt & 63;
    int tn = (pkt >> 6) & 1;
    int k2 = pkt >> 7;
    int oc = tn * 16 + (lane & 15);
    int kb = k2 * 32 + (lane >> 4) * 8;
    unsigned short v[8];
#pragma unroll
    for (int j = 0; j < 8; ++j) {
      int kk = kb + j;
      int kt = kk >> 8, c = kk & 255;
      v[j] = (oc < NOFF) ? f2bf(w_off[(oc * 256 + c) * 9 + kt]) : (unsigned short)0;
    }
    *(uint4*)&wOBf[(size_t)pkt * 8] = *(const uint4*)v;
  } else {
    if (threadIdx.x < 128) gstat[threadIdx.x] = 0.f;
  }
}

// ---------------------------------------------------------------------------
// offconv: tap-split x3 partials. Block (ts, b, i): taps ts*3..ts*3+2 of one
// image row; no LDS, no barriers; writes f32 partial om3[ts]. grid 768.
// ---------------------------------------------------------------------------
__global__ __launch_bounds__(256) void offconv_mfma_kernel(
    const unsigned short* __restrict__ xT, const unsigned short* __restrict__ wOBf,
    float* __restrict__ om3) {
  int bi = blockIdx.x;
  int ts = bi >> 8;
  int row = bi & 255;
  int b = row >> 6, i = row & 63;
  int t = threadIdx.x, lane = t & 63, wv = t >> 6;
  int lr = lane & 15, lq = lane >> 4;
  int p = wv * 16 + lr;
  const unsigned short* xb = xT + (size_t)b * (HW * 256);
  f32x4 acc[2] = {};

  for (int kc = 0; kc < 3; ++kc) {
    int kt = ts * 3 + kc;
    int ky = kt / 3, kx = kt % 3;
    int yy = i - 1 + ky, xx = p - 1 + kx;
    bool ok = ((unsigned)yy < 64u) && ((unsigned)xx < 64u);
    const unsigned short* ap = xb + ((ok ? yy * 64 + xx : 0) << 8) + lq * 8;
#pragma unroll
    for (int c8 = 0; c8 < 8; ++c8) {
      uint4 av = uint4{0, 0, 0, 0};
      if (ok) av = *(const uint4*)(ap + c8 * 32);
      int k2 = kt * 8 + c8;
      s16x8 a = __builtin_bit_cast(s16x8, av);
      s16x8 b0 = *(const s16x8*)(wOBf + ((((k2 * 2 + 0) << 6) | lane) << 3));
      s16x8 b1 = *(const s16x8*)(wOBf + ((((k2 * 2 + 1) << 6) | lane) << 3));
      acc[0] = __builtin_amdgcn_mfma_f32_16x16x32_bf16(a, b0, acc[0], 0, 0, 0);
      acc[1] = __builtin_amdgcn_mfma_f32_16x16x32_bf16(a, b1, acc[1], 0, 0, 0);
    }
  }
#pragma unroll
  for (int tn = 0; tn < 2; ++tn) {
    int oc = tn * 16 + lr;
    if (oc < NOFF) {
      float* ob = om3 + (size_t)ts * OM3S + ((b * NOFF + oc) << 12) + i * 64 + wv * 16;
#pragma unroll
      for (int r = 0; r < 4; ++r) ob[lq * 4 + r] = acc[tn][r];
    }
  }
}

// ---------------------------------------------------------------------------
// sampler: build im2col A[pix][k'] bf16 (k' = kt*256 + c). Block = 32 px of
// one image row; thread (p = t>>3, s = t&7). Barrier-free main loop. grid 512.
// ---------------------------------------------------------------------------
__global__ __launch_bounds__(256, 2) void sampler_kernel(
    const unsigned short* __restrict__ xT, const float* __restrict__ om3,
    const float* __restrict__ b_off, unsigned short* __restrict__ Aout) {
  __shared__ float tapw[32][KK][4];
  __shared__ int   tapc[32][KK][4];
  int bi = blockIdx.x;
  int b = bi >> 7, i = (bi >> 1) & 63, j0 = (bi & 1) * 32;
  int t = threadIdx.x;
  const unsigned short* xb = xT + (size_t)b * (HW * 256);

  for (int idx = t; idx < 32 * KK; idx += 256) {
    int p = idx / KK, k = idx % KK;
    int pix = i * 64 + j0 + p;
    size_t o = (size_t)(b * NOFF) * HW + pix;
    float offy = om3[o + k * HW] + om3[OM3S + o + k * HW] +
                 om3[2 * OM3S + o + k * HW] + b_off[k];
    float offx = om3[o + (9 + k) * HW] + om3[OM3S + o + (9 + k) * HW] +
                 om3[2 * OM3S + o + (9 + k) * HW] + b_off[9 + k];
    float mval = om3[o + (18 + k) * HW] + om3[OM3S + o + (18 + k) * HW] +
                 om3[2 * OM3S + o + (18 + k) * HW] + b_off[18 + k];
    float mask = 1.f / (1.f + __expf(-mval));
    float py = (float)(i - 1 + k / 3) + offy;
    float px = (float)(j0 + p - 1 + k % 3) + offx;
    float y0f = floorf(py), x0f = floorf(px);
    float wy1 = py - y0f, wx1 = px - x0f;
    int y0 = (int)y0f, x0 = (int)x0f;
    bool y0ok = (unsigned)y0 < 64u, y1ok = (unsigned)(y0 + 1) < 64u;
    bool x0ok = (unsigned)x0 < 64u, x1ok = (unsigned)(x0 + 1) < 64u;
    tapw[p][k][0] = (1.f - wy1) * (1.f - wx1) * mask * (float)(y0ok && x0ok);
    tapw[p][k][1] = (1.f - wy1) * wx1 * mask * (float)(y0ok && x1ok);
    tapw[p][k][2] = wy1 * (1.f - wx1) * mask * (float)(y1ok && x0ok);
    tapw[p][k][3] = wy1 * wx1 * mask * (float)(y1ok && x1ok);
    int y0c = min(max(y0, 0), 63), y1c = min(max(y0 + 1, 0), 63);
    int x0c = min(max(x0, 0), 63), x1c = min(max(x0 + 1, 0), 63);
    tapc[p][k][0] = (y0c * 64 + x0c) * 256;
    tapc[p][k][1] = (x1c - x0c) * 256;
    tapc[p][k][2] = (y1c - y0c) * 64 * 256;
    tapc[p][k][3] = 0;
  }
  __syncthreads();

  int p = t >> 3, s = t & 7;
  int gpix = b * 4096 + i * 64 + j0 + p;
  unsigned short* arow = Aout + (size_t)gpix * KC;

  for (int kt = 0; kt < KK; ++kt) {
    f32x4 tw = *(const f32x4*)&tapw[p][kt][0];
    float w00 = tw[0], w01 = tw[1], w10 = tw[2], w11 = tw[3];
    int4 tc = *(const int4*)&tapc[p][kt][0];
    const unsigned short* c00 = xb + tc.x + s * 8;
    int dx = tc.y, dy = tc.z;
#pragma unroll
    for (int g = 0; g < 4; ++g) {
      int c = g * 64 + s * 8;
      int cc = g * 64;
      uint4 v00 = *(const uint4*)(c00 + cc);
      uint4 v01 = *(const uint4*)(c00 + dx + cc);
      uint4 v10 = *(const uint4*)(c00 + dy + cc);
      uint4 v11 = *(const uint4*)(c00 + dy + dx + cc);
      const unsigned* a00 = (const unsigned*)&v00;
      const unsigned* a01 = (const unsigned*)&v01;
      const unsigned* a10 = (const unsigned*)&v10;
      const unsigned* a11 = (const unsigned*)&v11;
      uint4 res;
      unsigned* rr = (unsigned*)&res;
#pragma unroll
      for (int q = 0; q < 4; ++q) {
        float lo = w00 * bflo(a00[q]) + w01 * bflo(a01[q]) +
                   w10 * bflo(a10[q]) + w11 * bflo(a11[q]);
        float hi = w00 * bfhi(a00[q]) + w01 * bfhi(a01[q]) +
                   w10 * bfhi(a10[q]) + w11 * bfhi(a11[q]);
        rr[q] = packbf(lo, hi);
      }
      *(uint4*)(arow + kt * 256 + c) = res;
    }
  }
}

// ---------------------------------------------------------------------------
// gemm: C[16384][256] = A[16384][2304] * wTT[256][2304]^T, m97-shape.
// Tile 64(m) x 128(n), BK=32, global_load_lds staging, 4 waves (wave 32x64).
// grid 512 (n-minor for L2 A-reuse). Fused bias + bf16 store + GN partials.
// ---------------------------------------------------------------------------
__global__ __launch_bounds__(256, 2) void gemm_kernel(
    const unsigned short* __restrict__ A, const unsigned short* __restrict__ wTT,
    const float* __restrict__ bias, unsigned short* __restrict__ cvt,
    float* __restrict__ gstat) {
  __shared__ unsigned short At[64 * 32];     // row r at byte r*64
  __shared__ unsigned short Bt[128 * 32];
  int bi = blockIdx.x;
  int n0 = (bi & 1) * 128;
  int mrow = bi >> 1;                        // b*64 + i
  int m0 = mrow * 64;
  int t = threadIdx.x, lane = t & 63, wv = t >> 6;
  int mh = wv & 1, nh = wv >> 1;
  int lr = lane & 15, lq = lane >> 4;

  const char* Asrc = (const char*)A +
      (size_t)(m0 + wv * 16 + (lane >> 2)) * 4608 + (lane & 3) * 16;
  const char* Bsrc0 = (const char*)wTT +
      (size_t)(n0 + wv * 32 + (lane >> 2)) * 4608 + (lane & 3) * 16;
  const char* Bsrc1 = Bsrc0 + 16 * 4608;
  unsigned short* Alds = &At[wv * 512];
  unsigned short* Blds0 = &Bt[wv * 1024];
  unsigned short* Blds1 = &Bt[wv * 1024 + 512];

  f32x4 acc[2][4] = {};

  for (int ks = 0; ks < 72; ++ks) {
    int koff = ks * 64;                      // bytes along K
    gl2lds16(Asrc + koff, Alds);
    gl2lds16(Bsrc0 + koff, Blds0);
    gl2lds16(Bsrc1 + koff, Blds1);
    __syncthreads();
    s16x8 af[2], bf[4];
#pragma unroll
    for (int tm = 0; tm < 2; ++tm)
      af[tm] = *(const s16x8*)&At[(mh * 32 + tm * 16 + lr) * 32 + lq * 8];
#pragma unroll
    for (int tn = 0; tn < 4; ++tn)
      bf[tn] = *(const s16x8*)&Bt[(nh * 64 + tn * 16 + lr) * 32 + lq * 8];
#pragma unroll
    for (int tm = 0; tm < 2; ++tm)
#pragma unroll
      for (int tn = 0; tn < 4; ++tn)
        acc[tm][tn] = __builtin_amdgcn_mfma_f32_16x16x32_bf16(
            af[tm], bf[tn], acc[tm][tn], 0, 0, 0);
    __syncthreads();
  }

  int b = mrow >> 6, ii = mrow & 63;
#pragma unroll
  for (int tn = 0; tn < 4; ++tn) {
    int co = n0 + nh * 64 + tn * 16 + lr;
    float bco = bias[co];
    unsigned short* cvb = cvt + (size_t)(b * COUT + co) * HW + ii * 64;
    float s = 0.f, q = 0.f;
#pragma unroll
    for (int tm = 0; tm < 2; ++tm) {
      ushort4 st;
#pragma unroll
      for (int r = 0; r < 4; ++r) {
        float v = acc[tm][tn][r] + bco;
        s += v;
        q += v * v;
        ((unsigned short*)&st)[r] = f2bf(v);
      }
      *(ushort4*)(cvb + mh * 32 + tm * 16 + lq * 4) = st;
    }
#pragma unroll
    for (int off = 32; off > 0; off >>= 1) {
      s += __shfl_down(s, off, 64);
      q += __shfl_down(q, off, 64);
    }
    if (lane == 0) {
      int g = co >> 4;
      atomicAdd(&gstat[(b * 16 + g) * 2 + 0], s);
      atomicAdd(&gstat[(b * 16 + g) * 2 + 1], q);
    }
  }
}

// ---------------------------------------------------------------------------
// gn_apply: normalize bf16 convout -> f32 out. grid 2048.
// ---------------------------------------------------------------------------
__global__ __launch_bounds__(256) void gn_apply_kernel(
    const unsigned short* __restrict__ convout, const float* __restrict__ gstat,
    const float* __restrict__ gamma, const float* __restrict__ beta,
    float* __restrict__ out) {
  int vid = blockIdx.x * 256 + threadIdx.x;
  int e = vid * 8;
  int b = e >> 20;
  int c = (e >> 12) & 255;
  int g = c >> 4;
  float S = gstat[(b * 16 + g) * 2 + 0];
  float Q = gstat[(b * 16 + g) * 2 + 1];
  float mu = S * (1.f / 65536.f);
  float var = Q * (1.f / 65536.f) - mu * mu;
  float rs = rsqrtf(var + EPS);
  float a = rs * gamma[c];
  float bb = beta[c] - mu * a;
  uint4 v = *(const uint4*)(convout + e);
  const unsigned* u = (const unsigned*)&v;
  float4 o0, o1;
  o0.x = bflo(u[0]) * a + bb;  o0.y = bfhi(u[0]) * a + bb;
  o0.z = bflo(u[1]) * a + bb;  o0.w = bfhi(u[1]) * a + bb;
  o1.x = bflo(u[2]) * a + bb;  o1.y = bfhi(u[2]) * a + bb;
  o1.z = bflo(u[3]) * a + bb;  o1.w = bfhi(u[3]) * a + bb;
  *(float4*)(out + e) = o0;
  *(float4*)(out + e + 4) = o1;
}

// ---------------------------------------------------------------------------
extern "C" void kernel_launch(void* const* d_in, const int* in_sizes, int n_in,
                              void* d_out, int out_size, void* d_ws, size_t ws_size,
                              hipStream_t stream) {
  const float* x      = (const float*)d_in[0];
  const float* w_off  = (const float*)d_in[1];
  const float* b_off  = (const float*)d_in[2];
  const float* weight = (const float*)d_in[3];
  const float* bias   = (const float*)d_in[4];
  const float* gamma  = (const float*)d_in[5];
  const float* beta   = (const float*)d_in[6];
  float* out = (float*)d_out;

  // ws layout (~91 MB): om3 | xT(=cvt alias) | wTT | wOBf | A | gstat
  float* om3 = (float*)d_ws;                                  // 5.31 MB
  unsigned short* xT   = (unsigned short*)(om3 + (size_t)3 * OM3S);  // 8.39 MB
  unsigned short* cvt  = xT;                                  // alias: xT dead after sampler
  unsigned short* wTT  = xT + (size_t)B_ * HW * 256;          // 1.18 MB
  unsigned short* wOBf = wTT + (size_t)COUT * KC;             // 147 KB
  unsigned short* Abuf = wOBf + (size_t)32 * KC;              // 75.5 MB
  float* gstat = (float*)(Abuf + (size_t)B_ * HW * KC);       // 512 B

  xprep_kernel<<<dim3(B_ * 64), dim3(256), 0, stream>>>(x, xT);
  wprep_kernel<<<dim3(2341), dim3(256), 0, stream>>>(weight, w_off, wTT, wOBf, gstat);
  offconv_mfma_kernel<<<dim3(768), dim3(256), 0, stream>>>(xT, wOBf, om3);
  sampler_kernel<<<dim3(512), dim3(256), 0, stream>>>(xT, om3, b_off, Abuf);
  gemm_kernel<<<dim3(512), dim3(256), 0, stream>>>(Abuf, wTT, bias, cvt, gstat);
  gn_apply_kernel<<<dim3(2048), dim3(256), 0, stream>>>(cvt, gstat, gamma, beta, out);
}

// Round 7
// 212.218 us; speedup vs baseline: 7.9674x; 1.0377x over previous
//
#include <hip/hip_runtime.h>
#include <math.h>

#define CIN   256
#define COUT  256
#define H     64
#define W     64
#define HW    4096
#define KK    9
#define KC    2304
#define NOFF  27
#define B_    4
#define EPS   1e-5f
#define OM3S  (B_ * NOFF * HW)   // floats per offconv partial buffer

typedef __attribute__((ext_vector_type(4))) float f32x4;
typedef __attribute__((ext_vector_type(8))) short s16x8;

static __device__ __forceinline__ unsigned short f2bf(float f) {
  unsigned u = __builtin_bit_cast(unsigned, f);
  u += 0x7FFF + ((u >> 16) & 1);
  return (unsigned short)(u >> 16);
}
static __device__ __forceinline__ float bflo(unsigned u) {
  return __builtin_bit_cast(float, u << 16);
}
static __device__ __forceinline__ float bfhi(unsigned u) {
  return __builtin_bit_cast(float, u & 0xffff0000u);
}
static __device__ __forceinline__ unsigned packbf(float lo, float hi) {
  unsigned ul = __builtin_bit_cast(unsigned, lo);
  unsigned uh = __builtin_bit_cast(unsigned, hi);
  ul += 0x7FFF + ((ul >> 16) & 1);
  uh += 0x7FFF + ((uh >> 16) & 1);
  return (ul >> 16) | (uh & 0xffff0000u);
}
static __device__ __forceinline__ void gl2lds16(const void* g, void* l) {
  __builtin_amdgcn_global_load_lds(
      (const __attribute__((address_space(1))) unsigned int*)g,
      (__attribute__((address_space(3))) unsigned int*)l, 16, 0, 0);
}

// ---------------------------------------------------------------------------
// prep: fused xprep + wprep + gstat zero (one launch).
//  blocks [0,256):        x NCHW f32 -> xT NHWC bf16
//  blocks [256,2560):     wTT[co][kt*256+c] bf16 (GEMM B)
//  blocks [2560,2596):    wOBf fragment-order for offconv
//  block 2596:            zero gstat
// ---------------------------------------------------------------------------
__global__ __launch_bounds__(256) void prep_kernel(
    const float* __restrict__ x, const float* __restrict__ w,
    const float* __restrict__ w_off, unsigned short* __restrict__ xT,
    unsigned short* __restrict__ wTT, unsigned short* __restrict__ wOBf,
    float* __restrict__ gstat) {
  int bi = blockIdx.x;
  int t = threadIdx.x;
  if (bi < 256) {
    __shared__ unsigned short tile[64][272];
    int b = bi >> 6, y = bi & 63;
    const float* src = x + (size_t)b * CIN * HW + y * W;
    for (int r = 0; r < 64; ++r) {
      int idx = r * 256 + t;
      int c = idx >> 6, ww = idx & 63;
      tile[ww][c] = f2bf(src[(size_t)c * HW + ww]);
    }
    __syncthreads();
    unsigned short* dst = xT + ((size_t)(b * 64 + y) * 64) * 256;
    for (int r = 0; r < 8; ++r) {
      int idx = r * 2048 + t * 8;
      int ww = idx >> 8, c = idx & 255;
      *(uint4*)(dst + idx) = *(const uint4*)&tile[ww][c];
    }
  } else if (bi < 2560) {
    int idx = (bi - 256) * 256 + t;        // co*2304 + kt*256 + c
    int c  = idx & 255;
    int kt = (idx >> 8) % 9;
    int co = idx / KC;
    wTT[idx] = f2bf(w[(co * 256 + c) * 9 + kt]);
  } else if (bi < 2596) {
    int pkt = (bi - 2560) * 256 + t;       // [0, 9216)
    int lane = pkt & 63;
    int tn = (pkt >> 6) & 1;
    int k2 = pkt >> 7;
    int oc = tn * 16 + (lane & 15);
    int kb = k2 * 32 + (lane >> 4) * 8;
    unsigned short v[8];
#pragma unroll
    for (int j = 0; j < 8; ++j) {
      int kk = kb + j;
      int kt = kk >> 8, c = kk & 255;
      v[j] = (oc < NOFF) ? f2bf(w_off[(oc * 256 + c) * 9 + kt]) : (unsigned short)0;
    }
    *(uint4*)&wOBf[(size_t)pkt * 8] = *(const uint4*)v;
  } else {
    if (t < 128) gstat[t] = 0.f;
  }
}

// ---------------------------------------------------------------------------
// offconv: tap-split x3 partials, no LDS/barriers. grid 768.
// ---------------------------------------------------------------------------
__global__ __launch_bounds__(256) void offconv_mfma_kernel(
    const unsigned short* __restrict__ xT, const unsigned short* __restrict__ wOBf,
    float* __restrict__ om3) {
  int bi = blockIdx.x;
  int ts = bi >> 8;
  int row = bi & 255;
  int b = row >> 6, i = row & 63;
  int t = threadIdx.x, lane = t & 63, wv = t >> 6;
  int lr = lane & 15, lq = lane >> 4;
  int p = wv * 16 + lr;
  const unsigned short* xb = xT + (size_t)b * (HW * 256);
  f32x4 acc[2] = {};

  for (int kc = 0; kc < 3; ++kc) {
    int kt = ts * 3 + kc;
    int ky = kt / 3, kx = kt % 3;
    int yy = i - 1 + ky, xx = p - 1 + kx;
    bool ok = ((unsigned)yy < 64u) && ((unsigned)xx < 64u);
    const unsigned short* ap = xb + ((ok ? yy * 64 + xx : 0) << 8) + lq * 8;
#pragma unroll
    for (int c8 = 0; c8 < 8; ++c8) {
      uint4 av = uint4{0, 0, 0, 0};
      if (ok) av = *(const uint4*)(ap + c8 * 32);
      int k2 = kt * 8 + c8;
      s16x8 a = __builtin_bit_cast(s16x8, av);
      s16x8 b0 = *(const s16x8*)(wOBf + ((((k2 * 2 + 0) << 6) | lane) << 3));
      s16x8 b1 = *(const s16x8*)(wOBf + ((((k2 * 2 + 1) << 6) | lane) << 3));
      acc[0] = __builtin_amdgcn_mfma_f32_16x16x32_bf16(a, b0, acc[0], 0, 0, 0);
      acc[1] = __builtin_amdgcn_mfma_f32_16x16x32_bf16(a, b1, acc[1], 0, 0, 0);
    }
  }
#pragma unroll
  for (int tn = 0; tn < 2; ++tn) {
    int oc = tn * 16 + lr;
    if (oc < NOFF) {
      float* ob = om3 + (size_t)ts * OM3S + ((b * NOFF + oc) << 12) + i * 64 + wv * 16;
#pragma unroll
      for (int r = 0; r < 4; ++r) ob[lq * 4 + r] = acc[tn][r];
    }
  }
}

// ---------------------------------------------------------------------------
// sampler: build im2col A[pix][k'] bf16 (k' = kt*256 + c). grid 512.
// ---------------------------------------------------------------------------
__global__ __launch_bounds__(256, 2) void sampler_kernel(
    const unsigned short* __restrict__ xT, const float* __restrict__ om3,
    const float* __restrict__ b_off, unsigned short* __restrict__ Aout) {
  __shared__ float tapw[32][KK][4];
  __shared__ int   tapc[32][KK][4];
  int bi = blockIdx.x;
  int b = bi >> 7, i = (bi >> 1) & 63, j0 = (bi & 1) * 32;
  int t = threadIdx.x;
  const unsigned short* xb = xT + (size_t)b * (HW * 256);

  for (int idx = t; idx < 32 * KK; idx += 256) {
    int p = idx / KK, k = idx % KK;
    int pix = i * 64 + j0 + p;
    size_t o = (size_t)(b * NOFF) * HW + pix;
    float offy = om3[o + k * HW] + om3[OM3S + o + k * HW] +
                 om3[2 * OM3S + o + k * HW] + b_off[k];
    float offx = om3[o + (9 + k) * HW] + om3[OM3S + o + (9 + k) * HW] +
                 om3[2 * OM3S + o + (9 + k) * HW] + b_off[9 + k];
    float mval = om3[o + (18 + k) * HW] + om3[OM3S + o + (18 + k) * HW] +
                 om3[2 * OM3S + o + (18 + k) * HW] + b_off[18 + k];
    float mask = 1.f / (1.f + __expf(-mval));
    float py = (float)(i - 1 + k / 3) + offy;
    float px = (float)(j0 + p - 1 + k % 3) + offx;
    float y0f = floorf(py), x0f = floorf(px);
    float wy1 = py - y0f, wx1 = px - x0f;
    int y0 = (int)y0f, x0 = (int)x0f;
    bool y0ok = (unsigned)y0 < 64u, y1ok = (unsigned)(y0 + 1) < 64u;
    bool x0ok = (unsigned)x0 < 64u, x1ok = (unsigned)(x0 + 1) < 64u;
    tapw[p][k][0] = (1.f - wy1) * (1.f - wx1) * mask * (float)(y0ok && x0ok);
    tapw[p][k][1] = (1.f - wy1) * wx1 * mask * (float)(y0ok && x1ok);
    tapw[p][k][2] = wy1 * (1.f - wx1) * mask * (float)(y1ok && x0ok);
    tapw[p][k][3] = wy1 * wx1 * mask * (float)(y1ok && x1ok);
    int y0c = min(max(y0, 0), 63), y1c = min(max(y0 + 1, 0), 63);
    int x0c = min(max(x0, 0), 63), x1c = min(max(x0 + 1, 0), 63);
    tapc[p][k][0] = (y0c * 64 + x0c) * 256;
    tapc[p][k][1] = (x1c - x0c) * 256;
    tapc[p][k][2] = (y1c - y0c) * 64 * 256;
    tapc[p][k][3] = 0;
  }
  __syncthreads();

  int p = t >> 3, s = t & 7;
  int gpix = b * 4096 + i * 64 + j0 + p;
  unsigned short* arow = Aout + (size_t)gpix * KC;

  for (int kt = 0; kt < KK; ++kt) {
    f32x4 tw = *(const f32x4*)&tapw[p][kt][0];
    float w00 = tw[0], w01 = tw[1], w10 = tw[2], w11 = tw[3];
    int4 tc = *(const int4*)&tapc[p][kt][0];
    const unsigned short* c00 = xb + tc.x + s * 8;
    int dx = tc.y, dy = tc.z;
#pragma unroll
    for (int g = 0; g < 4; ++g) {
      int c = g * 64 + s * 8;
      int cc = g * 64;
      uint4 v00 = *(const uint4*)(c00 + cc);
      uint4 v01 = *(const uint4*)(c00 + dx + cc);
      uint4 v10 = *(const uint4*)(c00 + dy + cc);
      uint4 v11 = *(const uint4*)(c00 + dy + dx + cc);
      const unsigned* a00 = (const unsigned*)&v00;
      const unsigned* a01 = (const unsigned*)&v01;
      const unsigned* a10 = (const unsigned*)&v10;
      const unsigned* a11 = (const unsigned*)&v11;
      uint4 res;
      unsigned* rr = (unsigned*)&res;
#pragma unroll
      for (int q = 0; q < 4; ++q) {
        float lo = w00 * bflo(a00[q]) + w01 * bflo(a01[q]) +
                   w10 * bflo(a10[q]) + w11 * bflo(a11[q]);
        float hi = w00 * bfhi(a00[q]) + w01 * bfhi(a01[q]) +
                   w10 * bfhi(a10[q]) + w11 * bfhi(a11[q]);
        rr[q] = packbf(lo, hi);
      }
      *(uint4*)(arow + kt * 256 + c) = res;
    }
  }
}

// ---------------------------------------------------------------------------
// gemm: C[16384][256] = A[16384][2304] * wTT[256][2304]^T.
// Tile 64(m) x 128(n), BK=128 (18 iters), XOR-swizzled LDS (bank-conflict
// free), global_load_lds staging. 4 waves, wave tile 32x64. grid 512.
// Fused bias + bf16 store + GN partial stats.
// ---------------------------------------------------------------------------
__global__ __launch_bounds__(256, 2) void gemm_kernel(
    const unsigned short* __restrict__ A, const unsigned short* __restrict__ wTT,
    const float* __restrict__ bias, unsigned short* __restrict__ cvt,
    float* __restrict__ gstat) {
  __shared__ unsigned short At[64 * 128];    // 16 KB, row pitch 256 B
  __shared__ unsigned short Bt[128 * 128];   // 32 KB
  int bi = blockIdx.x;
  int n0 = (bi & 1) * 128;
  int mrow = bi >> 1;                        // b*64 + i
  int m0 = mrow * 64;
  int t = threadIdx.x, lane = t & 63, wv = t >> 6;
  int mh = wv & 1, nh = wv >> 1;
  int lr = lane & 15, lq = lane >> 4;

  // staging lane roles: rowq = lane>>4 (0..3), pos = lane&15; chunk = pos^(row&15)
  int rowq = lane >> 4, pos = lane & 15;

  f32x4 acc[2][4] = {};

  for (int ks = 0; ks < 18; ++ks) {
    int koff = ks * 256;                     // bytes along K
    // stage A: wave wv covers rows [wv*16, wv*16+16), 4 insts x 4 rows
#pragma unroll
    for (int q = 0; q < 4; ++q) {
      int r = wv * 16 + q * 4 + rowq;
      int c = pos ^ (r & 15);
      gl2lds16((const char*)A + (size_t)(m0 + r) * 4608 + c * 16 + koff,
               (char*)At + (wv * 16 + q * 4) * 256);
    }
    // stage B: wave wv covers rows [wv*32, wv*32+32), 8 insts x 4 rows
#pragma unroll
    for (int q = 0; q < 8; ++q) {
      int r = wv * 32 + q * 4 + rowq;
      int c = pos ^ (r & 15);
      gl2lds16((const char*)wTT + (size_t)(n0 + r) * 4608 + c * 16 + koff,
               (char*)Bt + (wv * 32 + q * 4) * 256);
    }
    __syncthreads();
#pragma unroll
    for (int kh = 0; kh < 4; ++kh) {
      s16x8 af[2], bf[4];
#pragma unroll
      for (int tm = 0; tm < 2; ++tm) {
        int r = mh * 32 + tm * 16 + lr;
        int pp = (kh * 4 + lq) ^ (r & 15);
        af[tm] = *(const s16x8*)((const char*)At + r * 256 + pp * 16);
      }
#pragma unroll
      for (int tn = 0; tn < 4; ++tn) {
        int r = nh * 64 + tn * 16 + lr;
        int pp = (kh * 4 + lq) ^ (r & 15);
        bf[tn] = *(const s16x8*)((const char*)Bt + r * 256 + pp * 16);
      }
#pragma unroll
      for (int tm = 0; tm < 2; ++tm)
#pragma unroll
        for (int tn = 0; tn < 4; ++tn)
          acc[tm][tn] = __builtin_amdgcn_mfma_f32_16x16x32_bf16(
              af[tm], bf[tn], acc[tm][tn], 0, 0, 0);
    }
    __syncthreads();
  }

  int b = mrow >> 6, ii = mrow & 63;
#pragma unroll
  for (int tn = 0; tn < 4; ++tn) {
    int co = n0 + nh * 64 + tn * 16 + lr;
    float bco = bias[co];
    unsigned short* cvb = cvt + (size_t)(b * COUT + co) * HW + ii * 64;
    float s = 0.f, q = 0.f;
#pragma unroll
    for (int tm = 0; tm < 2; ++tm) {
      ushort4 st;
#pragma unroll
      for (int r = 0; r < 4; ++r) {
        float v = acc[tm][tn][r] + bco;
        s += v;
        q += v * v;
        ((unsigned short*)&st)[r] = f2bf(v);
      }
      *(ushort4*)(cvb + mh * 32 + tm * 16 + lq * 4) = st;
    }
#pragma unroll
    for (int off = 32; off > 0; off >>= 1) {
      s += __shfl_down(s, off, 64);
      q += __shfl_down(q, off, 64);
    }
    if (lane == 0) {
      int g = co >> 4;
      atomicAdd(&gstat[(b * 16 + g) * 2 + 0], s);
      atomicAdd(&gstat[(b * 16 + g) * 2 + 1], q);
    }
  }
}

// ---------------------------------------------------------------------------
// gn_apply: normalize bf16 convout -> f32 out. grid 2048.
// ---------------------------------------------------------------------------
__global__ __launch_bounds__(256) void gn_apply_kernel(
    const unsigned short* __restrict__ convout, const float* __restrict__ gstat,
    const float* __restrict__ gamma, const float* __restrict__ beta,
    float* __restrict__ out) {
  int vid = blockIdx.x * 256 + threadIdx.x;
  int e = vid * 8;
  int b = e >> 20;
  int c = (e >> 12) & 255;
  int g = c >> 4;
  float S = gstat[(b * 16 + g) * 2 + 0];
  float Q = gstat[(b * 16 + g) * 2 + 1];
  float mu = S * (1.f / 65536.f);
  float var = Q * (1.f / 65536.f) - mu * mu;
  float rs = rsqrtf(var + EPS);
  float a = rs * gamma[c];
  float bb = beta[c] - mu * a;
  uint4 v = *(const uint4*)(convout + e);
  const unsigned* u = (const unsigned*)&v;
  float4 o0, o1;
  o0.x = bflo(u[0]) * a + bb;  o0.y = bfhi(u[0]) * a + bb;
  o0.z = bflo(u[1]) * a + bb;  o0.w = bfhi(u[1]) * a + bb;
  o1.x = bflo(u[2]) * a + bb;  o1.y = bfhi(u[2]) * a + bb;
  o1.z = bflo(u[3]) * a + bb;  o1.w = bfhi(u[3]) * a + bb;
  *(float4*)(out + e) = o0;
  *(float4*)(out + e + 4) = o1;
}

// ---------------------------------------------------------------------------
extern "C" void kernel_launch(void* const* d_in, const int* in_sizes, int n_in,
                              void* d_out, int out_size, void* d_ws, size_t ws_size,
                              hipStream_t stream) {
  const float* x      = (const float*)d_in[0];
  const float* w_off  = (const float*)d_in[1];
  const float* b_off  = (const float*)d_in[2];
  const float* weight = (const float*)d_in[3];
  const float* bias   = (const float*)d_in[4];
  const float* gamma  = (const float*)d_in[5];
  const float* beta   = (const float*)d_in[6];
  float* out = (float*)d_out;

  // ws layout (~91 MB): om3 | xT(=cvt alias) | wTT | wOBf | A | gstat
  float* om3 = (float*)d_ws;                                  // 5.31 MB
  unsigned short* xT   = (unsigned short*)(om3 + (size_t)3 * OM3S);  // 8.39 MB
  unsigned short* cvt  = xT;                                  // alias: xT dead after sampler
  unsigned short* wTT  = xT + (size_t)B_ * HW * 256;          // 1.18 MB
  unsigned short* wOBf = wTT + (size_t)COUT * KC;             // 147 KB
  unsigned short* Abuf = wOBf + (size_t)32 * KC;              // 75.5 MB
  float* gstat = (float*)(Abuf + (size_t)B_ * HW * KC);       // 512 B

  prep_kernel<<<dim3(2597), dim3(256), 0, stream>>>(x, weight, w_off, xT, wTT, wOBf, gstat);
  offconv_mfma_kernel<<<dim3(768), dim3(256), 0, stream>>>(xT, wOBf, om3);
  sampler_kernel<<<dim3(512), dim3(256), 0, stream>>>(xT, om3, b_off, Abuf);
  gemm_kernel<<<dim3(512), dim3(256), 0, stream>>>(Abuf, wTT, bias, cvt, gstat);
  gn_apply_kernel<<<dim3(2048), dim3(256), 0, stream>>>(cvt, gstat, gamma, beta, out);
}